// Round 8
// baseline (410.179 us; speedup 1.0000x reference)
//
#include <hip/hip_runtime.h>
#include <hip/hip_bf16.h>

// Mixer2dTriUKAN forward — bf16 MFMA; XCD-swizzled big GEMM, 2 blocks/CU,
// 2-deep register prefetch pipeline in all GEMMs.
//
// Algebraic simplifications (verified):
//  * sum(softmax(P),-1) == 1  =>  prob_distance/FFT pipeline is dead code.
//  * concat([x,x,x]) @ g_w.T == x @ (sum of the three 512-col blocks).T

#define M_ROWS 2048
#define TDIM   512
#define C4DIM  128
#define NFEAT  9
#define HZ     12      // split-K planes for the N=64 hidden GEMMs
#define BZ     8       // split-K planes for the big GEMMs

typedef unsigned short u16;
typedef __attribute__((ext_vector_type(8))) short short8;
typedef __attribute__((ext_vector_type(4))) float f32x4;

// ---------------------------------------------------------------------------
// helpers
// ---------------------------------------------------------------------------
__device__ __forceinline__ float bf2f(u16 u) {
    union { unsigned int i; float f; } c; c.i = ((unsigned int)u) << 16; return c.f;
}
__device__ __forceinline__ u16 f2bf(float v) {
    __hip_bfloat16 h = __float2bfloat16(v);
    return *reinterpret_cast<u16*>(&h);
}
__device__ __forceinline__ float siluf(float v) { return v / (1.0f + __expf(-v)); }
__device__ __forceinline__ float geluf(float v) {
    return 0.5f * v * (1.0f + erff(v * 0.70710678118654752440f));
}

// silu + 8 cubic B-spline bases on uniform grid g[i] = (i-3)*0.4 - 1
__device__ __forceinline__ void features9(float v, float* f) {
    f[0] = siluf(v);
    float b[11];
#pragma unroll
    for (int i = 0; i < 11; ++i) {
        float gi  = (float)(i - 3) * 0.4f - 1.0f;
        float gi1 = (float)(i - 2) * 0.4f - 1.0f;
        b[i] = (v >= gi && v < gi1) ? 1.0f : 0.0f;
    }
#pragma unroll
    for (int k = 1; k <= 3; ++k) {
#pragma unroll
        for (int i = 0; i + k < 11; ++i) {
            float gi   = (float)(i - 3) * 0.4f - 1.0f;
            float gi1  = (float)(i - 2) * 0.4f - 1.0f;
            float gik  = (float)(i + k - 3) * 0.4f - 1.0f;
            float gik1 = (float)(i + k - 2) * 0.4f - 1.0f;
            b[i] = (v - gi) * (1.0f / (gik - gi)) * b[i]
                 + (gik1 - v) * (1.0f / (gik1 - gi1)) * b[i + 1];
        }
    }
#pragma unroll
    for (int k = 0; k < 8; ++k) f[1 + k] = b[k];
}

// ---------------------------------------------------------------------------
// merged weight-prep kernel (one launch; block-range dispatch)
// ---------------------------------------------------------------------------
struct PrepPtrs {
    const float *g1_w, *g2_w;
    const float *b1, *s1, *b2, *s2, *b3, *s3, *b4, *s4, *b5, *s5, *b6, *s6;
    u16 *WE1, *WE2, *W1a, *W1b, *W2a, *W2b, *KX1, *KX2;
    const float *ln1w, *ln1b, *ln2w, *ln2b;
    float *LNT;   // 4 * 65536 transposed LN params
    float *SR;    // 64 floats of stats accumulators (zeroed here)
};

__device__ __forceinline__ void wcat_one(const float* bw, const float* sw, u16* out,
                                         int idx, int I) {
    int o = idx / I, i = idx - o * I;
    u16* w = out + (size_t)o * NFEAT * I;
    w[i] = f2bf(bw[idx]);
    const float* sp = sw + (size_t)idx * 8;
#pragma unroll
    for (int k = 0; k < 8; ++k) w[(1 + k) * I + i] = f2bf(sp[k]);
}

__global__ void prep_all(PrepPtrs p) {
    int blk = blockIdx.x, tid = threadIdx.x;
    if (blk < 2048) {                                   // weff x2
        const float* gw = blk < 1024 ? p.g1_w : p.g2_w;
        u16* we = blk < 1024 ? p.WE1 : p.WE2;
        int idx = (blk & 1023) * 256 + tid;
        int o = idx >> 9, i = idx & 511;
        const float* r = gw + (size_t)o * 1536;
        we[idx] = f2bf(r[i] + r[512 + i] + r[1024 + i]);
    } else if (blk < 2560) {                            // 4 small wcat (32768 each)
        int sub = blk - 2048, which = sub >> 7;
        int idx = (sub & 127) * 256 + tid;
        if (which == 0)      wcat_one(p.b1, p.s1, p.W1a, idx, 512);
        else if (which == 1) wcat_one(p.b2, p.s2, p.W1b, idx, 512);
        else if (which == 2) wcat_one(p.b3, p.s3, p.W2a, idx, 64);
        else                 wcat_one(p.b4, p.s4, p.W2b, idx, 64);
    } else if (blk < 4608) {                            // 2 big wcat (262144 each)
        int sub = blk - 2560;
        int idx = (sub & 1023) * 256 + tid;
        if (sub < 1024) wcat_one(p.b5, p.s5, p.KX1, idx, 512);
        else            wcat_one(p.b6, p.s6, p.KX2, idx, 512);
    } else if (blk < 5632) {                            // LN transpose x4
        int sub = blk - 4608, which = sub >> 8;
        const float* src = which == 0 ? p.ln1w : which == 1 ? p.ln1b
                         : which == 2 ? p.ln2w : p.ln2b;
        float* dst = p.LNT + (size_t)which * 65536;
        int idx = (sub & 255) * 256 + tid;              // idx = l*128 + c
        int c = idx & 127, l = idx >> 7;
        dst[c * 512 + l] = src[idx];
    } else {                                            // zero stats accumulators
        if (tid < 64) p.SR[tid] = 0.f;
    }
}

// ---------------------------------------------------------------------------
// stats stage 1 (branch 1): reads x f32, writes bf16 copy, accumulates sums
// ---------------------------------------------------------------------------
__global__ void stats1_convert(const float* __restrict__ X, u16* __restrict__ XB,
                               float* __restrict__ SR) {
    int idx = (blockIdx.x * 256 + threadIdx.x) * 4;
    float4 v = *reinterpret_cast<const float4*>(X + idx);
    ushort4 o; o.x = f2bf(v.x); o.y = f2bf(v.y); o.z = f2bf(v.z); o.w = f2bf(v.w);
    *reinterpret_cast<ushort4*>(XB + idx) = o;
    float s = v.x + v.y + v.z + v.w;
    float q = v.x * v.x + v.y * v.y + v.z * v.z + v.w * v.w;
#pragma unroll
    for (int off = 32; off > 0; off >>= 1) {
        s += __shfl_down(s, off);
        q += __shfl_down(q, off);
    }
    __shared__ float ls[4], lq[4];
    int wv = threadIdx.x >> 6;
    if ((threadIdx.x & 63) == 0) { ls[wv] = s; lq[wv] = q; }
    __syncthreads();
    if (threadIdx.x == 0) {
        s = ls[0] + ls[1] + ls[2] + ls[3];
        q = lq[0] + lq[1] + lq[2] + lq[3];
        int b = (blockIdx.x * 1024) >> 16;   // 64 blocks per batch
        atomicAdd(&SR[b * 2], s);
        atomicAdd(&SR[b * 2 + 1], q);
    }
}

// sum BZ split-K partials -> bf16 cm, and accumulate cm stats (branch 2)
__global__ void reduce8_bf16_stats(const float* __restrict__ P, u16* __restrict__ out,
                                   float* __restrict__ SR) {
    int idx = (blockIdx.x * 256 + threadIdx.x) * 4;
    const size_t PL = (size_t)M_ROWS * 512;
    float4 sv = *reinterpret_cast<const float4*>(P + idx);
#pragma unroll
    for (int z = 1; z < BZ; ++z) {
        float4 t = *reinterpret_cast<const float4*>(P + z * PL + idx);
        sv.x += t.x; sv.y += t.y; sv.z += t.z; sv.w += t.w;
    }
    ushort4 o; o.x = f2bf(sv.x); o.y = f2bf(sv.y); o.z = f2bf(sv.z); o.w = f2bf(sv.w);
    *reinterpret_cast<ushort4*>(out + idx) = o;
    float s = sv.x + sv.y + sv.z + sv.w;
    float q = sv.x * sv.x + sv.y * sv.y + sv.z * sv.z + sv.w * sv.w;
#pragma unroll
    for (int off = 32; off > 0; off >>= 1) {
        s += __shfl_down(s, off);
        q += __shfl_down(q, off);
    }
    __shared__ float ls[4], lq[4];
    int wv = threadIdx.x >> 6;
    if ((threadIdx.x & 63) == 0) { ls[wv] = s; lq[wv] = q; }
    __syncthreads();
    if (threadIdx.x == 0) {
        s = ls[0] + ls[1] + ls[2] + ls[3];
        q = lq[0] + lq[1] + lq[2] + lq[3];
        int b = (blockIdx.x * 1024) >> 16;
        atomicAdd(&SR[b * 2], s);
        atomicAdd(&SR[b * 2 + 1], q);
    }
}

// ---------------------------------------------------------------------------
// FEAT[m][j*512+i] (bf16); optional fused LayerNorm with inline mu/rstd
// ---------------------------------------------------------------------------
template<bool LN, bool INBF>
__global__ void build_feat(const void* __restrict__ X, const float* __restrict__ SR,
                           const float* __restrict__ lnwT, const float* __restrict__ lnbT,
                           u16* __restrict__ FEAT) {
    int i = blockIdx.x * blockDim.x + threadIdx.x;   // 0..511
    int m = blockIdx.y;                              // 0..2047
    float v = INBF ? bf2f(((const u16*)X)[(size_t)m * TDIM + i])
                   : ((const float*)X)[(size_t)m * TDIM + i];
    if (LN) {
        int b = m >> 7, c = m & 127;
        float mu   = SR[b * 2] * (1.0f / 65536.0f);
        float var  = SR[b * 2 + 1] * (1.0f / 65536.0f) - mu * mu;
        float rstd = rsqrtf(var + 1e-5f);
        v = (v - mu) * rstd * lnwT[c * 512 + i] + lnbT[c * 512 + i];
    }
    float f[NFEAT];
    features9(v, f);
    u16* out = FEAT + (size_t)m * (NFEAT * TDIM) + i;
#pragma unroll
    for (int j = 0; j < NFEAT; ++j) out[j * TDIM] = f2bf(f[j]);
}

// reduce HZ split-K partials (PART[z][m][64] f32) -> h1, then FEAT2[m][j*64+i] bf16
__global__ void build_feat2(const float* __restrict__ PART, u16* __restrict__ FEAT2) {
    int idx = blockIdx.x * blockDim.x + threadIdx.x;  // 2048*64
    int m = idx >> 6, i = idx & 63;
    float h = 0.f;
#pragma unroll
    for (int z = 0; z < HZ; ++z) h += PART[((size_t)z * M_ROWS + m) * 64 + i];
    float f[NFEAT];
    features9(h, f);
    u16* out = FEAT2 + (size_t)m * (NFEAT * 64) + i;
#pragma unroll
    for (int j = 0; j < NFEAT; ++j) out[j * 64] = f2bf(f[j]);
}

// out(f32) += sum of BZ split-K partials
__global__ void reduce8_add(const float* __restrict__ P, float* __restrict__ out) {
    int idx = (blockIdx.x * 256 + threadIdx.x) * 4;
    const size_t PL = (size_t)M_ROWS * 512;
    float4 s = *reinterpret_cast<float4*>(out + idx);
#pragma unroll
    for (int z = 0; z < BZ; ++z) {
        float4 t = *reinterpret_cast<const float4*>(P + z * PL + idx);
        s.x += t.x; s.y += t.y; s.z += t.z; s.w += t.w;
    }
    *reinterpret_cast<float4*>(out + idx) = s;
}

// ---------------------------------------------------------------------------
// BIG GEMM (M=2048, N=512, Kd=4608): 128x128 tile, 512 thr (8 waves, 2m x 4n),
// split-K z=BZ (kPerZ=576, 9 K-steps), grid = 512 blocks with XCD swizzle:
// XCD g gets one z-slice x all 64 (bm,bn) tiles -> 2.95 MB working set < 4MB L2.
// 2-deep register prefetch: loads for step t+2 issued at step t.
// ---------------------------------------------------------------------------
__global__ __launch_bounds__(512)
void gemm_big(const u16* __restrict__ A, const u16* __restrict__ B,
              float* __restrict__ Cout) {
    constexpr int Kd = 4608, kPerZ = Kd / BZ, NT = 512;
    constexpr int nt = kPerZ / 64;     // 9
    __shared__ u16 As[128][72];
    __shared__ u16 Bs[128][72];

    const int lin = blockIdx.x;
    const int sw  = (lin & 7) * 64 + (lin >> 3);   // bijective on [0,512)
    const int bn = (sw & 3) * 128;
    const int bm = ((sw >> 2) & 15) * 128;
    const int z  = sw >> 6;

    const int tid  = threadIdx.x;
    const int wave = tid >> 6, lane = tid & 63;
    const int wm = (wave >> 2) * 64, wn = (wave & 3) * 32;   // 2x4 wave grid
    const int lr = lane & 15, kh = lane >> 4;

    const u16* Ab = A + (size_t)bm * Kd + z * kPerZ;
    const u16* Bb = B + (size_t)bn * Kd + z * kPerZ;

    f32x4 acc[4][2];
#pragma unroll
    for (int a = 0; a < 4; ++a)
#pragma unroll
        for (int b = 0; b < 2; ++b) acc[a][b] = (f32x4){0.f, 0.f, 0.f, 0.f};

    uint4 arA[2], brA[2], arB[2], brB[2];

#define BLOADT(ar, br, kt)                                                          \
    {                                                                               \
        _Pragma("unroll")                                                           \
        for (int c = 0; c < 2; ++c) {                                               \
            int id = tid + c * 512;                                                 \
            ar[c] = *reinterpret_cast<const uint4*>(Ab + (size_t)(id >> 3) * Kd + (kt) + (id & 7) * 8); \
            br[c] = *reinterpret_cast<const uint4*>(Bb + (size_t)(id >> 3) * Kd + (kt) + (id & 7) * 8); \
        }                                                                           \
    }
#define BWRITET(ar, br)                                                             \
    {                                                                               \
        _Pragma("unroll")                                                           \
        for (int c = 0; c < 2; ++c) {                                               \
            int id = tid + c * 512;                                                 \
            *reinterpret_cast<uint4*>(&As[id >> 3][(id & 7) * 8]) = ar[c];          \
            *reinterpret_cast<uint4*>(&Bs[id >> 3][(id & 7) * 8]) = br[c];          \
        }                                                                           \
    }
#define BMFMAT()                                                                    \
    {                                                                               \
        _Pragma("unroll")                                                           \
        for (int ks = 0; ks < 2; ++ks) {                                            \
            short8 af[4], bfr[2];                                                   \
            _Pragma("unroll")                                                       \
            for (int a = 0; a < 4; ++a)                                             \
                af[a] = *reinterpret_cast<const short8*>(&As[wm + a * 16 + lr][ks * 32 + kh * 8]); \
            _Pragma("unroll")                                                       \
            for (int b = 0; b < 2; ++b)                                             \
                bfr[b] = *reinterpret_cast<const short8*>(&Bs[wn + b * 16 + lr][ks * 32 + kh * 8]); \
            _Pragma("unroll")                                                       \
            for (int a = 0; a < 4; ++a)                                             \
                _Pragma("unroll")                                                   \
                for (int b = 0; b < 2; ++b)                                         \
                    acc[a][b] = __builtin_amdgcn_mfma_f32_16x16x32_bf16(af[a], bfr[b], acc[a][b], 0, 0, 0); \
        }                                                                           \
    }

    BLOADT(arA, brA, 0);
    if (nt > 1) BLOADT(arB, brB, 64);
    int t = 0;
    for (; t + 1 < nt; t += 2) {
        __syncthreads();
        BWRITET(arA, brA);
        __syncthreads();
        if (t + 2 < nt) BLOADT(arA, brA, (t + 2) * 64);
        BMFMAT();
        __syncthreads();
        BWRITET(arB, brB);
        __syncthreads();
        if (t + 3 < nt) BLOADT(arB, brB, (t + 3) * 64);
        BMFMAT();
    }
    if (t < nt) {
        __syncthreads();
        BWRITET(arA, brA);
        __syncthreads();
        BMFMAT();
    }

    const int r0 = kh * 4;
#pragma unroll
    for (int a = 0; a < 4; ++a)
#pragma unroll
        for (int b = 0; b < 2; ++b)
#pragma unroll
            for (int r = 0; r < 4; ++r) {
                int row = bm + wm + a * 16 + r0 + r;
                int col = bn + wn + b * 16 + lr;
                Cout[((size_t)z * M_ROWS + row) * NT + col] = acc[a][b][r];
            }
}

// ---------------------------------------------------------------------------
// generic bf16 MFMA NT GEMM (hidden N=64 + small GEMMs)
// 256 threads = 4 waves (2x2), BK=64, reg-staged LDS (+8 u16 pad),
// 2-deep register prefetch.
// EPI 0: f32 store to plane blockIdx.z   EPI 1: bf16 acc + bf16 aux (residual)
// EPI 2: gelu(acc + f32 aux[n]) -> f32/bf16 per OUTF32
// ---------------------------------------------------------------------------
template<int BM, int BN, int EPI, bool OUTF32>
__global__ __launch_bounds__(256)
void gemm_mfma(const u16* __restrict__ A, const u16* __restrict__ B,
               void* __restrict__ Cout, const void* __restrict__ aux,
               int M, int N, int Kd, int kPerZ) {
    constexpr int WSM = BM / 2, WSN = BN / 2;
    constexpr int FM = WSM / 16, FN = WSN / 16;
    constexpr int CA = BM / 32, CB = BN / 32;
    __shared__ u16 As[BM][72];
    __shared__ u16 Bs[BN][72];

    const int tid  = threadIdx.x;
    const int wave = tid >> 6, lane = tid & 63;
    const int wm = (wave >> 1) * WSM, wn = (wave & 1) * WSN;
    const int lr = lane & 15, kh = lane >> 4;
    const int bm = blockIdx.y * BM, bn = blockIdx.x * BN;
    const int k0 = blockIdx.z * kPerZ;
    const int nt = kPerZ >> 6;

    const u16* Ab = A + (size_t)bm * Kd + k0;
    const u16* Bb = B + (size_t)bn * Kd + k0;

    f32x4 acc[FM][FN];
#pragma unroll
    for (int a = 0; a < FM; ++a)
#pragma unroll
        for (int b = 0; b < FN; ++b) acc[a][b] = (f32x4){0.f, 0.f, 0.f, 0.f};

    uint4 arA[CA], brA[CB], arB[CA], brB[CB];

#define GLOADT(ar, br, kt)                                                          \
    {                                                                               \
        _Pragma("unroll")                                                           \
        for (int c = 0; c < CA; ++c) {                                              \
            int id = tid + c * 256;                                                 \
            ar[c] = *reinterpret_cast<const uint4*>(Ab + (size_t)(id >> 3) * Kd + (kt) + (id & 7) * 8); \
        }                                                                           \
        _Pragma("unroll")                                                           \
        for (int c = 0; c < CB; ++c) {                                              \
            int id = tid + c * 256;                                                 \
            br[c] = *reinterpret_cast<const uint4*>(Bb + (size_t)(id >> 3) * Kd + (kt) + (id & 7) * 8); \
        }                                                                           \
    }
#define GWRITET(ar, br)                                                             \
    {                                                                               \
        _Pragma("unroll")                                                           \
        for (int c = 0; c < CA; ++c) {                                              \
            int id = tid + c * 256;                                                 \
            *reinterpret_cast<uint4*>(&As[id >> 3][(id & 7) * 8]) = ar[c];          \
        }                                                                           \
        _Pragma("unroll")                                                           \
        for (int c = 0; c < CB; ++c) {                                              \
            int id = tid + c * 256;                                                 \
            *reinterpret_cast<uint4*>(&Bs[id >> 3][(id & 7) * 8]) = br[c];          \
        }                                                                           \
    }
#define GMFMAT()                                                                    \
    {                                                                               \
        _Pragma("unroll")                                                           \
        for (int ks = 0; ks < 2; ++ks) {                                            \
            short8 af[FM], bfr[FN];                                                 \
            _Pragma("unroll")                                                       \
            for (int a = 0; a < FM; ++a)                                            \
                af[a] = *reinterpret_cast<const short8*>(&As[wm + a * 16 + lr][ks * 32 + kh * 8]); \
            _Pragma("unroll")                                                       \
            for (int b = 0; b < FN; ++b)                                            \
                bfr[b] = *reinterpret_cast<const short8*>(&Bs[wn + b * 16 + lr][ks * 32 + kh * 8]); \
            _Pragma("unroll")                                                       \
            for (int a = 0; a < FM; ++a)                                            \
                _Pragma("unroll")                                                   \
                for (int b = 0; b < FN; ++b)                                        \
                    acc[a][b] = __builtin_amdgcn_mfma_f32_16x16x32_bf16(af[a], bfr[b], acc[a][b], 0, 0, 0); \
        }                                                                           \
    }

    GLOADT(arA, brA, 0);
    if (nt > 1) GLOADT(arB, brB, 64);
    int t = 0;
    for (; t + 1 < nt; t += 2) {
        __syncthreads();
        GWRITET(arA, brA);
        __syncthreads();
        if (t + 2 < nt) GLOADT(arA, brA, (t + 2) * 64);
        GMFMAT();
        __syncthreads();
        GWRITET(arB, brB);
        __syncthreads();
        if (t + 3 < nt) GLOADT(arB, brB, (t + 3) * 64);
        GMFMAT();
    }
    if (t < nt) {
        __syncthreads();
        GWRITET(arA, brA);
        __syncthreads();
        GMFMAT();
    }

    const int r0 = kh * 4;   // D: row=(lane>>4)*4+reg, col=lane&15
#pragma unroll
    for (int a = 0; a < FM; ++a) {
#pragma unroll
        for (int b = 0; b < FN; ++b) {
#pragma unroll
            for (int r = 0; r < 4; ++r) {
                int row = bm + wm + a * 16 + r0 + r;
                int col = bn + wn + b * 16 + lr;
                float v = acc[a][b][r];
                if (EPI == 0) {
                    ((float*)Cout)[((size_t)blockIdx.z * M + row) * N + col] = v;
                } else if (EPI == 1) {
                    v += bf2f(((const u16*)aux)[(size_t)row * N + col]);
                    ((u16*)Cout)[(size_t)row * N + col] = f2bf(v);
                } else {  // EPI == 2
                    v = geluf(v + ((const float*)aux)[col]);
                    if (OUTF32) ((float*)Cout)[(size_t)row * N + col] = v;
                    else        ((u16*)Cout)[(size_t)row * N + col] = f2bf(v);
                }
            }
        }
    }
}

// ---------------------------------------------------------------------------
// launch
// ---------------------------------------------------------------------------
extern "C" void kernel_launch(void* const* d_in, const int* in_sizes, int n_in,
                              void* d_out, int out_size, void* d_ws, size_t ws_size,
                              hipStream_t stream) {
    const float* x            = (const float*)d_in[0];
    const float* tm1_ln_w     = (const float*)d_in[1];
    const float* tm1_ln_b     = (const float*)d_in[2];
    const float* tm1_k1_base  = (const float*)d_in[3];
    const float* tm1_k1_spl   = (const float*)d_in[4];
    const float* tm1_k2_base  = (const float*)d_in[5];
    const float* tm1_k2_spl   = (const float*)d_in[6];
    const float* g1_w         = (const float*)d_in[8];
    const float* g1_b         = (const float*)d_in[9];
    const float* k1_base      = (const float*)d_in[10];
    const float* k1_spl       = (const float*)d_in[11];
    const float* tm_ln_w      = (const float*)d_in[12];
    const float* tm_ln_b      = (const float*)d_in[13];
    const float* tm_k1_base   = (const float*)d_in[14];
    const float* tm_k1_spl    = (const float*)d_in[15];
    const float* tm_k2_base   = (const float*)d_in[16];
    const float* tm_k2_spl    = (const float*)d_in[17];
    const float* g2_w         = (const float*)d_in[19];
    const float* g2_b         = (const float*)d_in[20];
    const float* k2_base      = (const float*)d_in[21];
    const float* k2_spl       = (const float*)d_in[22];

    float* out = (float*)d_out;

    // ---- workspace layout (~77 MB) ---------------------------------------
    char* w = (char*)d_ws;
    u16*   FEAT  = (u16*)w;   w += (size_t)M_ROWS * 4608 * 2;
    u16*   FEAT2 = (u16*)w;   w += (size_t)M_ROWS * 576 * 2;
    float* PART  = (float*)w; w += (size_t)BZ * M_ROWS * 512 * 4;  // also HZ x 2048 x 64
    u16*   XB    = (u16*)w;   w += (size_t)M_ROWS * 512 * 2;
    u16*   BUF1  = (u16*)w;   w += (size_t)M_ROWS * 512 * 2;
    u16*   BUF2  = (u16*)w;   w += (size_t)M_ROWS * 512 * 2;
    u16*   BUF3  = (u16*)w;   w += (size_t)M_ROWS * 512 * 2;
    u16*   W1a   = (u16*)w;   w += (size_t)64 * 4608 * 2;
    u16*   W1b   = (u16*)w;   w += (size_t)64 * 4608 * 2;
    u16*   W2a   = (u16*)w;   w += (size_t)512 * 576 * 2;
    u16*   W2b   = (u16*)w;   w += (size_t)512 * 576 * 2;
    u16*   WE1   = (u16*)w;   w += (size_t)512 * 512 * 2;
    u16*   WE2   = (u16*)w;   w += (size_t)512 * 512 * 2;
    u16*   KX1   = (u16*)w;   w += (size_t)512 * 4608 * 2;
    u16*   KX2   = (u16*)w;   w += (size_t)512 * 4608 * 2;
    float* LNT   = (float*)w; w += (size_t)4 * 65536 * 4;
    float* SR    = (float*)w; w += 64 * 4;
    const float* LNT0w = LNT, *LNT0b = LNT + 65536;
    const float* LNT2w = LNT + 131072, *LNT2b = LNT + 196608;

    // ---- merged prep (weights, LN transpose, stats zeroing) ---------------
    PrepPtrs p;
    p.g1_w = g1_w; p.g2_w = g2_w;
    p.b1 = tm1_k1_base; p.s1 = tm1_k1_spl;
    p.b2 = tm_k1_base;  p.s2 = tm_k1_spl;
    p.b3 = tm1_k2_base; p.s3 = tm1_k2_spl;
    p.b4 = tm_k2_base;  p.s4 = tm_k2_spl;
    p.b5 = k1_base;     p.s5 = k1_spl;
    p.b6 = k2_base;     p.s6 = k2_spl;
    p.WE1 = WE1; p.WE2 = WE2; p.W1a = W1a; p.W1b = W1b;
    p.W2a = W2a; p.W2b = W2b; p.KX1 = KX1; p.KX2 = KX2;
    p.ln1w = tm1_ln_w; p.ln1b = tm1_ln_b; p.ln2w = tm_ln_w; p.ln2b = tm_ln_b;
    p.LNT = LNT; p.SR = SR;
    prep_all<<<5633, 256, 0, stream>>>(p);

    // ---- branch 1: tm1 = token_mixing(x); y1 = gelu(tm1 @ WE1 + b1) -> out
    stats1_convert<<<1024, 256, 0, stream>>>(x, XB, SR);
    build_feat<true, false><<<dim3(2, M_ROWS), 256, 0, stream>>>(x, SR, LNT0w, LNT0b, FEAT);
    gemm_mfma<64, 64, 0, true><<<dim3(1, 32, HZ), 256, 0, stream>>>(FEAT, W1a, PART, nullptr, M_ROWS, 64, 4608, 4608 / HZ);
    build_feat2<<<512, 256, 0, stream>>>(PART, FEAT2);
    gemm_mfma<64, 32, 1, false><<<dim3(16, 32, 1), 256, 0, stream>>>(FEAT2, W2a, BUF1, XB, M_ROWS, 512, 576, 576);
    gemm_mfma<64, 32, 2, true><<<dim3(16, 32, 1), 256, 0, stream>>>(BUF1, WE1, out, g1_b, M_ROWS, 512, 512, 512);

    // ---- branch 2: cm = kan(x); tm = token_mixing(cm); y2; z = kan(y2) ----
    build_feat<false, false><<<dim3(2, M_ROWS), 256, 0, stream>>>(x, nullptr, nullptr, nullptr, FEAT);
    gemm_big<<<512, 512, 0, stream>>>(FEAT, KX1, PART);
    reduce8_bf16_stats<<<1024, 256, 0, stream>>>(PART, BUF2, SR + 32);

    build_feat<true, true><<<dim3(2, M_ROWS), 256, 0, stream>>>(BUF2, SR + 32, LNT2w, LNT2b, FEAT);
    gemm_mfma<64, 64, 0, true><<<dim3(1, 32, HZ), 256, 0, stream>>>(FEAT, W1b, PART, nullptr, M_ROWS, 64, 4608, 4608 / HZ);
    build_feat2<<<512, 256, 0, stream>>>(PART, FEAT2);
    gemm_mfma<64, 32, 1, false><<<dim3(16, 32, 1), 256, 0, stream>>>(FEAT2, W2b, BUF1, BUF2, M_ROWS, 512, 576, 576);
    gemm_mfma<64, 32, 2, false><<<dim3(16, 32, 1), 256, 0, stream>>>(BUF1, WE2, BUF3, g2_b, M_ROWS, 512, 512, 512);

    build_feat<false, true><<<dim3(2, M_ROWS), 256, 0, stream>>>(BUF3, nullptr, nullptr, nullptr, FEAT);
    gemm_big<<<512, 512, 0, stream>>>(FEAT, KX2, PART);
    reduce8_add<<<1024, 256, 0, stream>>>(PART, out);
}

// Round 11
// 353.114 us; speedup vs baseline: 1.1616x; 1.1616x over previous
//
#include <hip/hip_runtime.h>
#include <hip/hip_bf16.h>

// Mixer2dTriUKAN forward — bf16 MFMA; big GEMM: global_load_lds + swizzled
// double-buffered LDS (m97 structure), XCD-swizzled 256-block grid, BZ=4.
//
// Algebraic simplifications (verified):
//  * sum(softmax(P),-1) == 1  =>  prob_distance/FFT pipeline is dead code.
//  * concat([x,x,x]) @ g_w.T == x @ (sum of the three 512-col blocks).T

#define M_ROWS 2048
#define TDIM   512
#define C4DIM  128
#define NFEAT  9
#define HZ     12      // split-K planes for the N=64 hidden GEMMs
#define BZ     4       // split-K planes for the big GEMMs

typedef unsigned short u16;
typedef __attribute__((ext_vector_type(8))) short short8;
typedef __attribute__((ext_vector_type(4))) float f32x4;

// ---------------------------------------------------------------------------
// helpers
// ---------------------------------------------------------------------------
__device__ __forceinline__ float bf2f(u16 u) {
    union { unsigned int i; float f; } c; c.i = ((unsigned int)u) << 16; return c.f;
}
__device__ __forceinline__ u16 f2bf(float v) {
    __hip_bfloat16 h = __float2bfloat16(v);
    return *reinterpret_cast<u16*>(&h);
}
__device__ __forceinline__ float siluf(float v) { return v / (1.0f + __expf(-v)); }
__device__ __forceinline__ float geluf(float v) {
    return 0.5f * v * (1.0f + erff(v * 0.70710678118654752440f));
}
__device__ __forceinline__ void gload16(const void* g, void* l) {
    __builtin_amdgcn_global_load_lds(
        (const __attribute__((address_space(1))) unsigned int*)g,
        (__attribute__((address_space(3))) unsigned int*)l, 16, 0, 0);
}

// silu + 8 cubic B-spline bases on uniform grid g[i] = (i-3)*0.4 - 1
__device__ __forceinline__ void features9(float v, float* f) {
    f[0] = siluf(v);
    float b[11];
#pragma unroll
    for (int i = 0; i < 11; ++i) {
        float gi  = (float)(i - 3) * 0.4f - 1.0f;
        float gi1 = (float)(i - 2) * 0.4f - 1.0f;
        b[i] = (v >= gi && v < gi1) ? 1.0f : 0.0f;
    }
#pragma unroll
    for (int k = 1; k <= 3; ++k) {
#pragma unroll
        for (int i = 0; i + k < 11; ++i) {
            float gi   = (float)(i - 3) * 0.4f - 1.0f;
            float gi1  = (float)(i - 2) * 0.4f - 1.0f;
            float gik  = (float)(i + k - 3) * 0.4f - 1.0f;
            float gik1 = (float)(i + k - 2) * 0.4f - 1.0f;
            b[i] = (v - gi) * (1.0f / (gik - gi)) * b[i]
                 + (gik1 - v) * (1.0f / (gik1 - gi1)) * b[i + 1];
        }
    }
#pragma unroll
    for (int k = 0; k < 8; ++k) f[1 + k] = b[k];
}

// ---------------------------------------------------------------------------
// merged weight-prep kernel (one launch; block-range dispatch)
// ---------------------------------------------------------------------------
struct PrepPtrs {
    const float *g1_w, *g2_w;
    const float *b1, *s1, *b2, *s2, *b3, *s3, *b4, *s4, *b5, *s5, *b6, *s6;
    u16 *WE1, *WE2, *W1a, *W1b, *W2a, *W2b, *KX1, *KX2;
    const float *ln1w, *ln1b, *ln2w, *ln2b;
    float *LNT;   // 4 * 65536 transposed LN params
    float *SR;    // 64 floats of stats accumulators (zeroed here)
};

__device__ __forceinline__ void wcat_one(const float* bw, const float* sw, u16* out,
                                         int idx, int I) {
    int o = idx / I, i = idx - o * I;
    u16* w = out + (size_t)o * NFEAT * I;
    w[i] = f2bf(bw[idx]);
    const float* sp = sw + (size_t)idx * 8;
#pragma unroll
    for (int k = 0; k < 8; ++k) w[(1 + k) * I + i] = f2bf(sp[k]);
}

__global__ void prep_all(PrepPtrs p) {
    int blk = blockIdx.x, tid = threadIdx.x;
    if (blk < 2048) {                                   // weff x2
        const float* gw = blk < 1024 ? p.g1_w : p.g2_w;
        u16* we = blk < 1024 ? p.WE1 : p.WE2;
        int idx = (blk & 1023) * 256 + tid;
        int o = idx >> 9, i = idx & 511;
        const float* r = gw + (size_t)o * 1536;
        we[idx] = f2bf(r[i] + r[512 + i] + r[1024 + i]);
    } else if (blk < 2560) {                            // 4 small wcat (32768 each)
        int sub = blk - 2048, which = sub >> 7;
        int idx = (sub & 127) * 256 + tid;
        if (which == 0)      wcat_one(p.b1, p.s1, p.W1a, idx, 512);
        else if (which == 1) wcat_one(p.b2, p.s2, p.W1b, idx, 512);
        else if (which == 2) wcat_one(p.b3, p.s3, p.W2a, idx, 64);
        else                 wcat_one(p.b4, p.s4, p.W2b, idx, 64);
    } else if (blk < 4608) {                            // 2 big wcat (262144 each)
        int sub = blk - 2560;
        int idx = (sub & 1023) * 256 + tid;
        if (sub < 1024) wcat_one(p.b5, p.s5, p.KX1, idx, 512);
        else            wcat_one(p.b6, p.s6, p.KX2, idx, 512);
    } else if (blk < 5632) {                            // LN transpose x4
        int sub = blk - 4608, which = sub >> 8;
        const float* src = which == 0 ? p.ln1w : which == 1 ? p.ln1b
                         : which == 2 ? p.ln2w : p.ln2b;
        float* dst = p.LNT + (size_t)which * 65536;
        int idx = (sub & 255) * 256 + tid;              // idx = l*128 + c
        int c = idx & 127, l = idx >> 7;
        dst[c * 512 + l] = src[idx];
    } else {                                            // zero stats accumulators
        if (tid < 64) p.SR[tid] = 0.f;
    }
}

// ---------------------------------------------------------------------------
// stats stage 1 (branch 1): reads x f32, writes bf16 copy, accumulates sums
// ---------------------------------------------------------------------------
__global__ void stats1_convert(const float* __restrict__ X, u16* __restrict__ XB,
                               float* __restrict__ SR) {
    int idx = (blockIdx.x * 256 + threadIdx.x) * 4;
    float4 v = *reinterpret_cast<const float4*>(X + idx);
    ushort4 o; o.x = f2bf(v.x); o.y = f2bf(v.y); o.z = f2bf(v.z); o.w = f2bf(v.w);
    *reinterpret_cast<ushort4*>(XB + idx) = o;
    float s = v.x + v.y + v.z + v.w;
    float q = v.x * v.x + v.y * v.y + v.z * v.z + v.w * v.w;
#pragma unroll
    for (int off = 32; off > 0; off >>= 1) {
        s += __shfl_down(s, off);
        q += __shfl_down(q, off);
    }
    __shared__ float ls[4], lq[4];
    int wv = threadIdx.x >> 6;
    if ((threadIdx.x & 63) == 0) { ls[wv] = s; lq[wv] = q; }
    __syncthreads();
    if (threadIdx.x == 0) {
        s = ls[0] + ls[1] + ls[2] + ls[3];
        q = lq[0] + lq[1] + lq[2] + lq[3];
        int b = (blockIdx.x * 1024) >> 16;   // 64 blocks per batch
        atomicAdd(&SR[b * 2], s);
        atomicAdd(&SR[b * 2 + 1], q);
    }
}

// sum BZ split-K partials -> bf16 cm, and accumulate cm stats (branch 2)
__global__ void reduce4_bf16_stats(const float* __restrict__ P, u16* __restrict__ out,
                                   float* __restrict__ SR) {
    int idx = (blockIdx.x * 256 + threadIdx.x) * 4;
    const size_t PL = (size_t)M_ROWS * 512;
    float4 sv = *reinterpret_cast<const float4*>(P + idx);
#pragma unroll
    for (int z = 1; z < BZ; ++z) {
        float4 t = *reinterpret_cast<const float4*>(P + z * PL + idx);
        sv.x += t.x; sv.y += t.y; sv.z += t.z; sv.w += t.w;
    }
    ushort4 o; o.x = f2bf(sv.x); o.y = f2bf(sv.y); o.z = f2bf(sv.z); o.w = f2bf(sv.w);
    *reinterpret_cast<ushort4*>(out + idx) = o;
    float s = sv.x + sv.y + sv.z + sv.w;
    float q = sv.x * sv.x + sv.y * sv.y + sv.z * sv.z + sv.w * sv.w;
#pragma unroll
    for (int off = 32; off > 0; off >>= 1) {
        s += __shfl_down(s, off);
        q += __shfl_down(q, off);
    }
    __shared__ float ls[4], lq[4];
    int wv = threadIdx.x >> 6;
    if ((threadIdx.x & 63) == 0) { ls[wv] = s; lq[wv] = q; }
    __syncthreads();
    if (threadIdx.x == 0) {
        s = ls[0] + ls[1] + ls[2] + ls[3];
        q = lq[0] + lq[1] + lq[2] + lq[3];
        int b = (blockIdx.x * 1024) >> 16;
        atomicAdd(&SR[b * 2], s);
        atomicAdd(&SR[b * 2 + 1], q);
    }
}

// ---------------------------------------------------------------------------
// FEAT[m][j*512+i] (bf16); optional fused LayerNorm with inline mu/rstd
// ---------------------------------------------------------------------------
template<bool LN, bool INBF>
__global__ void build_feat(const void* __restrict__ X, const float* __restrict__ SR,
                           const float* __restrict__ lnwT, const float* __restrict__ lnbT,
                           u16* __restrict__ FEAT) {
    int i = blockIdx.x * blockDim.x + threadIdx.x;   // 0..511
    int m = blockIdx.y;                              // 0..2047
    float v = INBF ? bf2f(((const u16*)X)[(size_t)m * TDIM + i])
                   : ((const float*)X)[(size_t)m * TDIM + i];
    if (LN) {
        int b = m >> 7, c = m & 127;
        float mu   = SR[b * 2] * (1.0f / 65536.0f);
        float var  = SR[b * 2 + 1] * (1.0f / 65536.0f) - mu * mu;
        float rstd = rsqrtf(var + 1e-5f);
        v = (v - mu) * rstd * lnwT[c * 512 + i] + lnbT[c * 512 + i];
    }
    float f[NFEAT];
    features9(v, f);
    u16* out = FEAT + (size_t)m * (NFEAT * TDIM) + i;
#pragma unroll
    for (int j = 0; j < NFEAT; ++j) out[j * TDIM] = f2bf(f[j]);
}

// reduce HZ split-K partials (PART[z][m][64] f32) -> h1, then FEAT2[m][j*64+i] bf16
__global__ void build_feat2(const float* __restrict__ PART, u16* __restrict__ FEAT2) {
    int idx = blockIdx.x * blockDim.x + threadIdx.x;  // 2048*64
    int m = idx >> 6, i = idx & 63;
    float h = 0.f;
#pragma unroll
    for (int z = 0; z < HZ; ++z) h += PART[((size_t)z * M_ROWS + m) * 64 + i];
    float f[NFEAT];
    features9(h, f);
    u16* out = FEAT2 + (size_t)m * (NFEAT * 64) + i;
#pragma unroll
    for (int j = 0; j < NFEAT; ++j) out[j * 64] = f2bf(f[j]);
}

// out(f32) += sum of BZ split-K partials
__global__ void reduce4_add(const float* __restrict__ P, float* __restrict__ out) {
    int idx = (blockIdx.x * 256 + threadIdx.x) * 4;
    const size_t PL = (size_t)M_ROWS * 512;
    float4 s = *reinterpret_cast<float4*>(out + idx);
#pragma unroll
    for (int z = 0; z < BZ; ++z) {
        float4 t = *reinterpret_cast<const float4*>(P + z * PL + idx);
        s.x += t.x; s.y += t.y; s.z += t.z; s.w += t.w;
    }
    *reinterpret_cast<float4*>(out + idx) = s;
}

// ---------------------------------------------------------------------------
// BIG GEMM (M=2048, N=512, Kd=4608): 128x128 tile, 512 thr (8 waves, 2m x 4n),
// split-K z=BZ=4 (kPerZ=1152, 18 K-steps), grid = 256 blocks, XCD swizzle.
// Staging: __builtin_amdgcn_global_load_lds (16B) into double-buffered LDS.
// LDS is linear [128][64]; bank conflicts on ds_read_b128 avoided by XOR
// swizzle applied on the GLOBAL source address (slot ^= row&7) and on the
// LDS read address — both-sides-or-neither (G21/m173).
// One barrier per K-step: barrier drains vmcnt (buf[cur] ready), then loads
// for t+1 are issued into buf[cur^1] and fly under the MFMA phase.
// ---------------------------------------------------------------------------
__global__ __launch_bounds__(512)
void gemm_big(const u16* __restrict__ A, const u16* __restrict__ B,
              float* __restrict__ Cout) {
    constexpr int Kd = 4608, kPerZ = Kd / BZ, NT = 512;
    constexpr int nt = kPerZ / 64;     // 18
    __shared__ u16 As[2][128][64];
    __shared__ u16 Bs[2][128][64];

    const int lin = blockIdx.x;
    const int sw  = (lin & 7) * 32 + (lin >> 3);   // bijective on [0,256)
    const int bn = (sw & 3) * 128;
    const int bm = ((sw >> 2) & 15) * 128;
    const int z  = sw >> 6;

    const int tid  = threadIdx.x;
    const int wave = tid >> 6, lane = tid & 63;
    const int wm = (wave >> 2) * 64, wn = (wave & 3) * 32;   // 2x4 wave grid
    const int lr = lane & 15, kh = lane >> 4;

    const u16* Ab = A + (size_t)bm * Kd + z * kPerZ;
    const u16* Bb = B + (size_t)bn * Kd + z * kPerZ;

    // staging geometry: chunk ci = wave*2+c covers LDS rows [ci*8, ci*8+8).
    // DMA: lane l lands at row ci*8 + (l>>3), 16B-slot l&7. Pre-swizzled
    // global source so LDS slot s holds k-elems (s ^ (row&7))*8 .. +8.
    const int l3  = lane >> 3;                     // row-within-chunk = row&7
    const int swz = ((lane & 7) ^ l3) * 8;         // k-elem offset within 64

    f32x4 acc[4][2];
#pragma unroll
    for (int a = 0; a < 4; ++a)
#pragma unroll
        for (int b = 0; b < 2; ++b) acc[a][b] = (f32x4){0.f, 0.f, 0.f, 0.f};

#define BIG_ISSUE(buf, kt)                                                     \
    {                                                                          \
        _Pragma("unroll")                                                      \
        for (int c = 0; c < 2; ++c) {                                          \
            int ci = wave * 2 + c;                                             \
            int row = ci * 8 + l3;                                             \
            gload16(Ab + (size_t)row * Kd + (kt) + swz, &As[buf][ci * 8][0]);  \
            gload16(Bb + (size_t)row * Kd + (kt) + swz, &Bs[buf][ci * 8][0]);  \
        }                                                                      \
    }

    BIG_ISSUE(0, 0);
    int cur = 0;
    for (int t = 0; t < nt; ++t) {
        __syncthreads();                       // drains vmcnt: buf[cur] ready
        if (t + 1 < nt) BIG_ISSUE(cur ^ 1, (t + 1) * 64);
#pragma unroll
        for (int ks = 0; ks < 2; ++ks) {
            short8 af[4], bfr[2];
#pragma unroll
            for (int a = 0; a < 4; ++a) {
                int row = wm + a * 16 + lr;
                af[a] = *reinterpret_cast<const short8*>(
                    &As[cur][row][((ks * 4 + kh) ^ (lr & 7)) * 8]);
            }
#pragma unroll
            for (int b = 0; b < 2; ++b) {
                int row = wn + b * 16 + lr;
                bfr[b] = *reinterpret_cast<const short8*>(
                    &Bs[cur][row][((ks * 4 + kh) ^ (lr & 7)) * 8]);
            }
#pragma unroll
            for (int a = 0; a < 4; ++a)
#pragma unroll
                for (int b = 0; b < 2; ++b)
                    acc[a][b] = __builtin_amdgcn_mfma_f32_16x16x32_bf16(af[a], bfr[b], acc[a][b], 0, 0, 0);
        }
        cur ^= 1;
    }

    const int r0 = kh * 4;
#pragma unroll
    for (int a = 0; a < 4; ++a)
#pragma unroll
        for (int b = 0; b < 2; ++b)
#pragma unroll
            for (int r = 0; r < 4; ++r) {
                int row = bm + wm + a * 16 + r0 + r;
                int col = bn + wn + b * 16 + lr;
                Cout[((size_t)z * M_ROWS + row) * NT + col] = acc[a][b][r];
            }
}

// ---------------------------------------------------------------------------
// generic bf16 MFMA NT GEMM (hidden N=64 + small GEMMs)
// 256 threads = 4 waves (2x2), BK=64, reg-staged LDS (+8 u16 pad),
// 2-deep register prefetch.
// EPI 0: f32 store to plane blockIdx.z   EPI 1: bf16 acc + bf16 aux (residual)
// EPI 2: gelu(acc + f32 aux[n]) -> f32/bf16 per OUTF32
// ---------------------------------------------------------------------------
template<int BM, int BN, int EPI, bool OUTF32>
__global__ __launch_bounds__(256)
void gemm_mfma(const u16* __restrict__ A, const u16* __restrict__ B,
               void* __restrict__ Cout, const void* __restrict__ aux,
               int M, int N, int Kd, int kPerZ) {
    constexpr int WSM = BM / 2, WSN = BN / 2;
    constexpr int FM = WSM / 16, FN = WSN / 16;
    constexpr int CA = BM / 32, CB = BN / 32;
    __shared__ u16 As[BM][72];
    __shared__ u16 Bs[BN][72];

    const int tid  = threadIdx.x;
    const int wave = tid >> 6, lane = tid & 63;
    const int wm = (wave >> 1) * WSM, wn = (wave & 1) * WSN;
    const int lr = lane & 15, kh = lane >> 4;
    const int bm = blockIdx.y * BM, bn = blockIdx.x * BN;
    const int k0 = blockIdx.z * kPerZ;
    const int nt = kPerZ >> 6;

    const u16* Ab = A + (size_t)bm * Kd + k0;
    const u16* Bb = B + (size_t)bn * Kd + k0;

    f32x4 acc[FM][FN];
#pragma unroll
    for (int a = 0; a < FM; ++a)
#pragma unroll
        for (int b = 0; b < FN; ++b) acc[a][b] = (f32x4){0.f, 0.f, 0.f, 0.f};

    uint4 arA[CA], brA[CB], arB[CA], brB[CB];

#define GLOADT(ar, br, kt)                                                          \
    {                                                                               \
        _Pragma("unroll")                                                           \
        for (int c = 0; c < CA; ++c) {                                              \
            int id = tid + c * 256;                                                 \
            ar[c] = *reinterpret_cast<const uint4*>(Ab + (size_t)(id >> 3) * Kd + (kt) + (id & 7) * 8); \
        }                                                                           \
        _Pragma("unroll")                                                           \
        for (int c = 0; c < CB; ++c) {                                              \
            int id = tid + c * 256;                                                 \
            br[c] = *reinterpret_cast<const uint4*>(Bb + (size_t)(id >> 3) * Kd + (kt) + (id & 7) * 8); \
        }                                                                           \
    }
#define GWRITET(ar, br)                                                             \
    {                                                                               \
        _Pragma("unroll")                                                           \
        for (int c = 0; c < CA; ++c) {                                              \
            int id = tid + c * 256;                                                 \
            *reinterpret_cast<uint4*>(&As[id >> 3][(id & 7) * 8]) = ar[c];          \
        }                                                                           \
        _Pragma("unroll")                                                           \
        for (int c = 0; c < CB; ++c) {                                              \
            int id = tid + c * 256;                                                 \
            *reinterpret_cast<uint4*>(&Bs[id >> 3][(id & 7) * 8]) = br[c];          \
        }                                                                           \
    }
#define GMFMAT()                                                                    \
    {                                                                               \
        _Pragma("unroll")                                                           \
        for (int ks = 0; ks < 2; ++ks) {                                            \
            short8 af[FM], bfr[FN];                                                 \
            _Pragma("unroll")                                                       \
            for (int a = 0; a < FM; ++a)                                            \
                af[a] = *reinterpret_cast<const short8*>(&As[wm + a * 16 + lr][ks * 32 + kh * 8]); \
            _Pragma("unroll")                                                       \
            for (int b = 0; b < FN; ++b)                                            \
                bfr[b] = *reinterpret_cast<const short8*>(&Bs[wn + b * 16 + lr][ks * 32 + kh * 8]); \
            _Pragma("unroll")                                                       \
            for (int a = 0; a < FM; ++a)                                            \
                _Pragma("unroll")                                                   \
                for (int b = 0; b < FN; ++b)                                        \
                    acc[a][b] = __builtin_amdgcn_mfma_f32_16x16x32_bf16(af[a], bfr[b], acc[a][b], 0, 0, 0); \
        }                                                                           \
    }

    GLOADT(arA, brA, 0);
    if (nt > 1) GLOADT(arB, brB, 64);
    int t = 0;
    for (; t + 1 < nt; t += 2) {
        __syncthreads();
        GWRITET(arA, brA);
        __syncthreads();
        if (t + 2 < nt) GLOADT(arA, brA, (t + 2) * 64);
        GMFMAT();
        __syncthreads();
        GWRITET(arB, brB);
        __syncthreads();
        if (t + 3 < nt) GLOADT(arB, brB, (t + 3) * 64);
        GMFMAT();
    }
    if (t < nt) {
        __syncthreads();
        GWRITET(arA, brA);
        __syncthreads();
        GMFMAT();
    }

    const int r0 = kh * 4;   // D: row=(lane>>4)*4+reg, col=lane&15
#pragma unroll
    for (int a = 0; a < FM; ++a) {
#pragma unroll
        for (int b = 0; b < FN; ++b) {
#pragma unroll
            for (int r = 0; r < 4; ++r) {
                int row = bm + wm + a * 16 + r0 + r;
                int col = bn + wn + b * 16 + lr;
                float v = acc[a][b][r];
                if (EPI == 0) {
                    ((float*)Cout)[((size_t)blockIdx.z * M + row) * N + col] = v;
                } else if (EPI == 1) {
                    v += bf2f(((const u16*)aux)[(size_t)row * N + col]);
                    ((u16*)Cout)[(size_t)row * N + col] = f2bf(v);
                } else {  // EPI == 2
                    v = geluf(v + ((const float*)aux)[col]);
                    if (OUTF32) ((float*)Cout)[(size_t)row * N + col] = v;
                    else        ((u16*)Cout)[(size_t)row * N + col] = f2bf(v);
                }
            }
        }
    }
}

// ---------------------------------------------------------------------------
// launch
// ---------------------------------------------------------------------------
extern "C" void kernel_launch(void* const* d_in, const int* in_sizes, int n_in,
                              void* d_out, int out_size, void* d_ws, size_t ws_size,
                              hipStream_t stream) {
    const float* x            = (const float*)d_in[0];
    const float* tm1_ln_w     = (const float*)d_in[1];
    const float* tm1_ln_b     = (const float*)d_in[2];
    const float* tm1_k1_base  = (const float*)d_in[3];
    const float* tm1_k1_spl   = (const float*)d_in[4];
    const float* tm1_k2_base  = (const float*)d_in[5];
    const float* tm1_k2_spl   = (const float*)d_in[6];
    const float* g1_w         = (const float*)d_in[8];
    const float* g1_b         = (const float*)d_in[9];
    const float* k1_base      = (const float*)d_in[10];
    const float* k1_spl       = (const float*)d_in[11];
    const float* tm_ln_w      = (const float*)d_in[12];
    const float* tm_ln_b      = (const float*)d_in[13];
    const float* tm_k1_base   = (const float*)d_in[14];
    const float* tm_k1_spl    = (const float*)d_in[15];
    const float* tm_k2_base   = (const float*)d_in[16];
    const float* tm_k2_spl    = (const float*)d_in[17];
    const float* g2_w         = (const float*)d_in[19];
    const float* g2_b         = (const float*)d_in[20];
    const float* k2_base      = (const float*)d_in[21];
    const float* k2_spl       = (const float*)d_in[22];

    float* out = (float*)d_out;

    // ---- workspace layout -------------------------------------------------
    char* w = (char*)d_ws;
    u16*   FEAT  = (u16*)w;   w += (size_t)M_ROWS * 4608 * 2;
    u16*   FEAT2 = (u16*)w;   w += (size_t)M_ROWS * 576 * 2;
    float* PART  = (float*)w; w += (size_t)BZ * M_ROWS * 512 * 4;  // also HZ x 2048 x 64
    u16*   XB    = (u16*)w;   w += (size_t)M_ROWS * 512 * 2;
    u16*   BUF1  = (u16*)w;   w += (size_t)M_ROWS * 512 * 2;
    u16*   BUF2  = (u16*)w;   w += (size_t)M_ROWS * 512 * 2;
    u16*   BUF3  = (u16*)w;   w += (size_t)M_ROWS * 512 * 2;
    u16*   W1a   = (u16*)w;   w += (size_t)64 * 4608 * 2;
    u16*   W1b   = (u16*)w;   w += (size_t)64 * 4608 * 2;
    u16*   W2a   = (u16*)w;   w += (size_t)512 * 576 * 2;
    u16*   W2b   = (u16*)w;   w += (size_t)512 * 576 * 2;
    u16*   WE1   = (u16*)w;   w += (size_t)512 * 512 * 2;
    u16*   WE2   = (u16*)w;   w += (size_t)512 * 512 * 2;
    u16*   KX1   = (u16*)w;   w += (size_t)512 * 4608 * 2;
    u16*   KX2   = (u16*)w;   w += (size_t)512 * 4608 * 2;
    float* LNT   = (float*)w; w += (size_t)4 * 65536 * 4;
    float* SR    = (float*)w; w += 64 * 4;
    const float* LNT0w = LNT, *LNT0b = LNT + 65536;
    const float* LNT2w = LNT + 131072, *LNT2b = LNT + 196608;

    // ---- merged prep (weights, LN transpose, stats zeroing) ---------------
    PrepPtrs p;
    p.g1_w = g1_w; p.g2_w = g2_w;
    p.b1 = tm1_k1_base; p.s1 = tm1_k1_spl;
    p.b2 = tm_k1_base;  p.s2 = tm_k1_spl;
    p.b3 = tm1_k2_base; p.s3 = tm1_k2_spl;
    p.b4 = tm_k2_base;  p.s4 = tm_k2_spl;
    p.b5 = k1_base;     p.s5 = k1_spl;
    p.b6 = k2_base;     p.s6 = k2_spl;
    p.WE1 = WE1; p.WE2 = WE2; p.W1a = W1a; p.W1b = W1b;
    p.W2a = W2a; p.W2b = W2b; p.KX1 = KX1; p.KX2 = KX2;
    p.ln1w = tm1_ln_w; p.ln1b = tm1_ln_b; p.ln2w = tm_ln_w; p.ln2b = tm_ln_b;
    p.LNT = LNT; p.SR = SR;
    prep_all<<<5633, 256, 0, stream>>>(p);

    // ---- branch 1: tm1 = token_mixing(x); y1 = gelu(tm1 @ WE1 + b1) -> out
    stats1_convert<<<1024, 256, 0, stream>>>(x, XB, SR);
    build_feat<true, false><<<dim3(2, M_ROWS), 256, 0, stream>>>(x, SR, LNT0w, LNT0b, FEAT);
    gemm_mfma<64, 64, 0, true><<<dim3(1, 32, HZ), 256, 0, stream>>>(FEAT, W1a, PART, nullptr, M_ROWS, 64, 4608, 4608 / HZ);
    build_feat2<<<512, 256, 0, stream>>>(PART, FEAT2);
    gemm_mfma<64, 32, 1, false><<<dim3(16, 32, 1), 256, 0, stream>>>(FEAT2, W2a, BUF1, XB, M_ROWS, 512, 576, 576);
    gemm_mfma<64, 32, 2, true><<<dim3(16, 32, 1), 256, 0, stream>>>(BUF1, WE1, out, g1_b, M_ROWS, 512, 512, 512);

    // ---- branch 2: cm = kan(x); tm = token_mixing(cm); y2; z = kan(y2) ----
    build_feat<false, false><<<dim3(2, M_ROWS), 256, 0, stream>>>(x, nullptr, nullptr, nullptr, FEAT);
    gemm_big<<<256, 512, 0, stream>>>(FEAT, KX1, PART);
    reduce4_bf16_stats<<<1024, 256, 0, stream>>>(PART, BUF2, SR + 32);

    build_feat<true, true><<<dim3(2, M_ROWS), 256, 0, stream>>>(BUF2, SR + 32, LNT2w, LNT2b, FEAT);
    gemm_mfma<64, 64, 0, true><<<dim3(1, 32, HZ), 256, 0, stream>>>(FEAT, W1b, PART, nullptr, M_ROWS, 64, 4608, 4608 / HZ);
    build_feat2<<<512, 256, 0, stream>>>(PART, FEAT2);
    gemm_mfma<64, 32, 1, false><<<dim3(16, 32, 1), 256, 0, stream>>>(FEAT2, W2b, BUF1, BUF2, M_ROWS, 512, 576, 576);
    gemm_mfma<64, 32, 2, false><<<dim3(16, 32, 1), 256, 0, stream>>>(BUF1, WE2, BUF3, g2_b, M_ROWS, 512, 512, 512);

    build_feat<false, true><<<dim3(2, M_ROWS), 256, 0, stream>>>(BUF3, nullptr, nullptr, nullptr, FEAT);
    gemm_big<<<256, 512, 0, stream>>>(FEAT, KX2, PART);
    reduce4_add<<<1024, 256, 0, stream>>>(PART, out);
}

// Round 12
// 341.943 us; speedup vs baseline: 1.1996x; 1.0327x over previous
//
#include <hip/hip_runtime.h>
#include <hip/hip_bf16.h>

// Mixer2dTriUKAN forward — bf16 MFMA; fused feature-expansion epilogues,
// dual-output feature builder; big GEMM: global_load_lds + swizzled
// double-buffered LDS, XCD-swizzled 256-block grid, BZ=4.
//
// Algebraic simplifications (verified):
//  * sum(softmax(P),-1) == 1  =>  prob_distance/FFT pipeline is dead code.
//  * concat([x,x,x]) @ g_w.T == x @ (sum of the three 512-col blocks).T

#define M_ROWS 2048
#define TDIM   512
#define C4DIM  128
#define NFEAT  9
#define HZ     12      // split-K planes for the N=64 hidden GEMMs
#define BZ     4       // split-K planes for the big GEMMs

typedef unsigned short u16;
typedef __attribute__((ext_vector_type(8))) short short8;
typedef __attribute__((ext_vector_type(4))) float f32x4;

// ---------------------------------------------------------------------------
// helpers
// ---------------------------------------------------------------------------
__device__ __forceinline__ float bf2f(u16 u) {
    union { unsigned int i; float f; } c; c.i = ((unsigned int)u) << 16; return c.f;
}
__device__ __forceinline__ u16 f2bf(float v) {
    __hip_bfloat16 h = __float2bfloat16(v);
    return *reinterpret_cast<u16*>(&h);
}
__device__ __forceinline__ float siluf(float v) { return v / (1.0f + __expf(-v)); }
__device__ __forceinline__ float geluf(float v) {
    return 0.5f * v * (1.0f + erff(v * 0.70710678118654752440f));
}
__device__ __forceinline__ void gload16(const void* g, void* l) {
    __builtin_amdgcn_global_load_lds(
        (const __attribute__((address_space(1))) unsigned int*)g,
        (__attribute__((address_space(3))) unsigned int*)l, 16, 0, 0);
}

// silu + 8 cubic B-spline bases on uniform grid g[i] = (i-3)*0.4 - 1
__device__ __forceinline__ void features9(float v, float* f) {
    f[0] = siluf(v);
    float b[11];
#pragma unroll
    for (int i = 0; i < 11; ++i) {
        float gi  = (float)(i - 3) * 0.4f - 1.0f;
        float gi1 = (float)(i - 2) * 0.4f - 1.0f;
        b[i] = (v >= gi && v < gi1) ? 1.0f : 0.0f;
    }
#pragma unroll
    for (int k = 1; k <= 3; ++k) {
#pragma unroll
        for (int i = 0; i + k < 11; ++i) {
            float gi   = (float)(i - 3) * 0.4f - 1.0f;
            float gi1  = (float)(i - 2) * 0.4f - 1.0f;
            float gik  = (float)(i + k - 3) * 0.4f - 1.0f;
            float gik1 = (float)(i + k - 2) * 0.4f - 1.0f;
            b[i] = (v - gi) * (1.0f / (gik - gi)) * b[i]
                 + (gik1 - v) * (1.0f / (gik1 - gi1)) * b[i + 1];
        }
    }
#pragma unroll
    for (int k = 0; k < 8; ++k) f[1 + k] = b[k];
}

// ---------------------------------------------------------------------------
// merged weight-prep kernel (one launch; block-range dispatch)
// ---------------------------------------------------------------------------
struct PrepPtrs {
    const float *g1_w, *g2_w;
    const float *b1, *s1, *b2, *s2, *b3, *s3, *b4, *s4, *b5, *s5, *b6, *s6;
    u16 *WE1, *WE2, *W1a, *W1b, *W2a, *W2b, *KX1, *KX2;
    const float *ln1w, *ln1b, *ln2w, *ln2b;
    float *LNT;   // 4 * 65536 transposed LN params
    float *SR;    // 64 floats of stats accumulators (zeroed here)
};

__device__ __forceinline__ void wcat_one(const float* bw, const float* sw, u16* out,
                                         int idx, int I) {
    int o = idx / I, i = idx - o * I;
    u16* w = out + (size_t)o * NFEAT * I;
    w[i] = f2bf(bw[idx]);
    const float* sp = sw + (size_t)idx * 8;
#pragma unroll
    for (int k = 0; k < 8; ++k) w[(1 + k) * I + i] = f2bf(sp[k]);
}

__global__ void prep_all(PrepPtrs p) {
    int blk = blockIdx.x, tid = threadIdx.x;
    if (blk < 2048) {                                   // weff x2
        const float* gw = blk < 1024 ? p.g1_w : p.g2_w;
        u16* we = blk < 1024 ? p.WE1 : p.WE2;
        int idx = (blk & 1023) * 256 + tid;
        int o = idx >> 9, i = idx & 511;
        const float* r = gw + (size_t)o * 1536;
        we[idx] = f2bf(r[i] + r[512 + i] + r[1024 + i]);
    } else if (blk < 2560) {                            // 4 small wcat (32768 each)
        int sub = blk - 2048, which = sub >> 7;
        int idx = (sub & 127) * 256 + tid;
        if (which == 0)      wcat_one(p.b1, p.s1, p.W1a, idx, 512);
        else if (which == 1) wcat_one(p.b2, p.s2, p.W1b, idx, 512);
        else if (which == 2) wcat_one(p.b3, p.s3, p.W2a, idx, 64);
        else                 wcat_one(p.b4, p.s4, p.W2b, idx, 64);
    } else if (blk < 4608) {                            // 2 big wcat (262144 each)
        int sub = blk - 2560;
        int idx = (sub & 1023) * 256 + tid;
        if (sub < 1024) wcat_one(p.b5, p.s5, p.KX1, idx, 512);
        else            wcat_one(p.b6, p.s6, p.KX2, idx, 512);
    } else if (blk < 5632) {                            // LN transpose x4
        int sub = blk - 4608, which = sub >> 8;
        const float* src = which == 0 ? p.ln1w : which == 1 ? p.ln1b
                         : which == 2 ? p.ln2w : p.ln2b;
        float* dst = p.LNT + (size_t)which * 65536;
        int idx = (sub & 255) * 256 + tid;              // idx = l*128 + c
        int c = idx & 127, l = idx >> 7;
        dst[c * 512 + l] = src[idx];
    } else {                                            // zero stats accumulators
        if (tid < 64) p.SR[tid] = 0.f;
    }
}

// ---------------------------------------------------------------------------
// stats stage 1 (branch 1): reads x f32, writes bf16 copy, accumulates sums
// ---------------------------------------------------------------------------
__global__ void stats1_convert(const float* __restrict__ X, u16* __restrict__ XB,
                               float* __restrict__ SR) {
    int idx = (blockIdx.x * 256 + threadIdx.x) * 4;
    float4 v = *reinterpret_cast<const float4*>(X + idx);
    ushort4 o; o.x = f2bf(v.x); o.y = f2bf(v.y); o.z = f2bf(v.z); o.w = f2bf(v.w);
    *reinterpret_cast<ushort4*>(XB + idx) = o;
    float s = v.x + v.y + v.z + v.w;
    float q = v.x * v.x + v.y * v.y + v.z * v.z + v.w * v.w;
#pragma unroll
    for (int off = 32; off > 0; off >>= 1) {
        s += __shfl_down(s, off);
        q += __shfl_down(q, off);
    }
    __shared__ float ls[4], lq[4];
    int wv = threadIdx.x >> 6;
    if ((threadIdx.x & 63) == 0) { ls[wv] = s; lq[wv] = q; }
    __syncthreads();
    if (threadIdx.x == 0) {
        s = ls[0] + ls[1] + ls[2] + ls[3];
        q = lq[0] + lq[1] + lq[2] + lq[3];
        int b = (blockIdx.x * 1024) >> 16;   // 64 blocks per batch
        atomicAdd(&SR[b * 2], s);
        atomicAdd(&SR[b * 2 + 1], q);
    }
}

// sum BZ split-K partials -> bf16 cm, and accumulate cm stats (branch 2)
__global__ void reduce4_bf16_stats(const float* __restrict__ P, u16* __restrict__ out,
                                   float* __restrict__ SR) {
    int idx = (blockIdx.x * 256 + threadIdx.x) * 4;
    const size_t PL = (size_t)M_ROWS * 512;
    float4 sv = *reinterpret_cast<const float4*>(P + idx);
#pragma unroll
    for (int z = 1; z < BZ; ++z) {
        float4 t = *reinterpret_cast<const float4*>(P + z * PL + idx);
        sv.x += t.x; sv.y += t.y; sv.z += t.z; sv.w += t.w;
    }
    ushort4 o; o.x = f2bf(sv.x); o.y = f2bf(sv.y); o.z = f2bf(sv.z); o.w = f2bf(sv.w);
    *reinterpret_cast<ushort4*>(out + idx) = o;
    float s = sv.x + sv.y + sv.z + sv.w;
    float q = sv.x * sv.x + sv.y * sv.y + sv.z * sv.z + sv.w * sv.w;
#pragma unroll
    for (int off = 32; off > 0; off >>= 1) {
        s += __shfl_down(s, off);
        q += __shfl_down(q, off);
    }
    __shared__ float ls[4], lq[4];
    int wv = threadIdx.x >> 6;
    if ((threadIdx.x & 63) == 0) { ls[wv] = s; lq[wv] = q; }
    __syncthreads();
    if (threadIdx.x == 0) {
        s = ls[0] + ls[1] + ls[2] + ls[3];
        q = lq[0] + lq[1] + lq[2] + lq[3];
        int b = (blockIdx.x * 1024) >> 16;
        atomicAdd(&SR[b * 2], s);
        atomicAdd(&SR[b * 2 + 1], q);
    }
}

// ---------------------------------------------------------------------------
// feature builders (vectorized x4): 2048 blocks x 128 threads
// ---------------------------------------------------------------------------

// branch1 LN features -> FA, branch2 plain features -> FB (single x read)
__global__ void build_feat_dual(const float* __restrict__ X, const float* __restrict__ SR,
                                const float* __restrict__ lnwT, const float* __restrict__ lnbT,
                                u16* __restrict__ FA, u16* __restrict__ FB) {
    int m = blockIdx.x;
    int i0 = threadIdx.x * 4;
    float4 xv = *reinterpret_cast<const float4*>(X + (size_t)m * TDIM + i0);
    int b = m >> 7, c = m & 127;
    float mu   = SR[b * 2] * (1.0f / 65536.0f);
    float var  = SR[b * 2 + 1] * (1.0f / 65536.0f) - mu * mu;
    float rstd = rsqrtf(var + 1e-5f);
    float4 lw = *reinterpret_cast<const float4*>(lnwT + (size_t)c * 512 + i0);
    float4 lb = *reinterpret_cast<const float4*>(lnbT + (size_t)c * 512 + i0);
    float fb[4][NFEAT], fa[4][NFEAT];
    float xe[4] = {xv.x, xv.y, xv.z, xv.w};
    float lwv[4] = {lw.x, lw.y, lw.z, lw.w};
    float lbv[4] = {lb.x, lb.y, lb.z, lb.w};
#pragma unroll
    for (int e = 0; e < 4; ++e) {
        features9(xe[e], fb[e]);
        features9((xe[e] - mu) * rstd * lwv[e] + lbv[e], fa[e]);
    }
    u16* oa = FA + (size_t)m * (NFEAT * TDIM) + i0;
    u16* ob = FB + (size_t)m * (NFEAT * TDIM) + i0;
#pragma unroll
    for (int j = 0; j < NFEAT; ++j) {
        ushort4 va, vb;
        va.x = f2bf(fa[0][j]); va.y = f2bf(fa[1][j]);
        va.z = f2bf(fa[2][j]); va.w = f2bf(fa[3][j]);
        vb.x = f2bf(fb[0][j]); vb.y = f2bf(fb[1][j]);
        vb.z = f2bf(fb[2][j]); vb.w = f2bf(fb[3][j]);
        *reinterpret_cast<ushort4*>(oa + j * TDIM) = va;
        *reinterpret_cast<ushort4*>(ob + j * TDIM) = vb;
    }
}

// LN features from bf16 input (branch2: cm -> FEAT)
__global__ void build_feat_ln(const u16* __restrict__ X, const float* __restrict__ SR,
                              const float* __restrict__ lnwT, const float* __restrict__ lnbT,
                              u16* __restrict__ FA) {
    int m = blockIdx.x;
    int i0 = threadIdx.x * 4;
    ushort4 xu = *reinterpret_cast<const ushort4*>(X + (size_t)m * TDIM + i0);
    int b = m >> 7, c = m & 127;
    float mu   = SR[b * 2] * (1.0f / 65536.0f);
    float var  = SR[b * 2 + 1] * (1.0f / 65536.0f) - mu * mu;
    float rstd = rsqrtf(var + 1e-5f);
    float4 lw = *reinterpret_cast<const float4*>(lnwT + (size_t)c * 512 + i0);
    float4 lb = *reinterpret_cast<const float4*>(lnbT + (size_t)c * 512 + i0);
    float fa[4][NFEAT];
    float xe[4] = {bf2f(xu.x), bf2f(xu.y), bf2f(xu.z), bf2f(xu.w)};
    float lwv[4] = {lw.x, lw.y, lw.z, lw.w};
    float lbv[4] = {lb.x, lb.y, lb.z, lb.w};
#pragma unroll
    for (int e = 0; e < 4; ++e)
        features9((xe[e] - mu) * rstd * lwv[e] + lbv[e], fa[e]);
    u16* oa = FA + (size_t)m * (NFEAT * TDIM) + i0;
#pragma unroll
    for (int j = 0; j < NFEAT; ++j) {
        ushort4 va;
        va.x = f2bf(fa[0][j]); va.y = f2bf(fa[1][j]);
        va.z = f2bf(fa[2][j]); va.w = f2bf(fa[3][j]);
        *reinterpret_cast<ushort4*>(oa + j * TDIM) = va;
    }
}

// reduce HZ split-K partials (PART[z][m][64] f32) -> h1, then FEAT2[m][j*64+i] bf16
__global__ void build_feat2(const float* __restrict__ PART, u16* __restrict__ FEAT2) {
    int idx = blockIdx.x * blockDim.x + threadIdx.x;  // 2048*64
    int m = idx >> 6, i = idx & 63;
    float h = 0.f;
#pragma unroll
    for (int z = 0; z < HZ; ++z) h += PART[((size_t)z * M_ROWS + m) * 64 + i];
    float f[NFEAT];
    features9(h, f);
    u16* out = FEAT2 + (size_t)m * (NFEAT * 64) + i;
#pragma unroll
    for (int j = 0; j < NFEAT; ++j) out[j * 64] = f2bf(f[j]);
}

// out(f32) += sum of BZ split-K partials
__global__ void reduce4_add(const float* __restrict__ P, float* __restrict__ out) {
    int idx = (blockIdx.x * 256 + threadIdx.x) * 4;
    const size_t PL = (size_t)M_ROWS * 512;
    float4 s = *reinterpret_cast<float4*>(out + idx);
#pragma unroll
    for (int z = 0; z < BZ; ++z) {
        float4 t = *reinterpret_cast<const float4*>(P + z * PL + idx);
        s.x += t.x; s.y += t.y; s.z += t.z; s.w += t.w;
    }
    *reinterpret_cast<float4*>(out + idx) = s;
}

// ---------------------------------------------------------------------------
// BIG GEMM (M=2048, N=512, Kd=4608): 128x128 tile, 512 thr (8 waves, 2m x 4n),
// split-K z=BZ=4 (kPerZ=1152, 18 K-steps), grid = 256 blocks, XCD swizzle.
// global_load_lds into double-buffered LDS; both-sides XOR swizzle.
// ---------------------------------------------------------------------------
__global__ __launch_bounds__(512)
void gemm_big(const u16* __restrict__ A, const u16* __restrict__ B,
              float* __restrict__ Cout) {
    constexpr int Kd = 4608, kPerZ = Kd / BZ, NT = 512;
    constexpr int nt = kPerZ / 64;     // 18
    __shared__ u16 As[2][128][64];
    __shared__ u16 Bs[2][128][64];

    const int lin = blockIdx.x;
    const int sw  = (lin & 7) * 32 + (lin >> 3);   // bijective on [0,256)
    const int bn = (sw & 3) * 128;
    const int bm = ((sw >> 2) & 15) * 128;
    const int z  = sw >> 6;

    const int tid  = threadIdx.x;
    const int wave = tid >> 6, lane = tid & 63;
    const int wm = (wave >> 2) * 64, wn = (wave & 3) * 32;   // 2x4 wave grid
    const int lr = lane & 15, kh = lane >> 4;

    const u16* Ab = A + (size_t)bm * Kd + z * kPerZ;
    const u16* Bb = B + (size_t)bn * Kd + z * kPerZ;

    const int l3  = lane >> 3;                     // row-within-chunk = row&7
    const int swz = ((lane & 7) ^ l3) * 8;         // k-elem offset within 64

    f32x4 acc[4][2];
#pragma unroll
    for (int a = 0; a < 4; ++a)
#pragma unroll
        for (int b = 0; b < 2; ++b) acc[a][b] = (f32x4){0.f, 0.f, 0.f, 0.f};

#define BIG_ISSUE(buf, kt)                                                     \
    {                                                                          \
        _Pragma("unroll")                                                      \
        for (int c = 0; c < 2; ++c) {                                          \
            int ci = wave * 2 + c;                                             \
            int row = ci * 8 + l3;                                             \
            gload16(Ab + (size_t)row * Kd + (kt) + swz, &As[buf][ci * 8][0]);  \
            gload16(Bb + (size_t)row * Kd + (kt) + swz, &Bs[buf][ci * 8][0]);  \
        }                                                                      \
    }

    BIG_ISSUE(0, 0);
    int cur = 0;
    for (int t = 0; t < nt; ++t) {
        __syncthreads();                       // drains vmcnt: buf[cur] ready
        if (t + 1 < nt) BIG_ISSUE(cur ^ 1, (t + 1) * 64);
#pragma unroll
        for (int ks = 0; ks < 2; ++ks) {
            short8 af[4], bfr[2];
#pragma unroll
            for (int a = 0; a < 4; ++a) {
                int row = wm + a * 16 + lr;
                af[a] = *reinterpret_cast<const short8*>(
                    &As[cur][row][((ks * 4 + kh) ^ (lr & 7)) * 8]);
            }
#pragma unroll
            for (int b = 0; b < 2; ++b) {
                int row = wn + b * 16 + lr;
                bfr[b] = *reinterpret_cast<const short8*>(
                    &Bs[cur][row][((ks * 4 + kh) ^ (lr & 7)) * 8]);
            }
#pragma unroll
            for (int a = 0; a < 4; ++a)
#pragma unroll
                for (int b = 0; b < 2; ++b)
                    acc[a][b] = __builtin_amdgcn_mfma_f32_16x16x32_bf16(af[a], bfr[b], acc[a][b], 0, 0, 0);
        }
        cur ^= 1;
    }

    const int r0 = kh * 4;
#pragma unroll
    for (int a = 0; a < 4; ++a)
#pragma unroll
        for (int b = 0; b < 2; ++b)
#pragma unroll
            for (int r = 0; r < 4; ++r) {
                int row = bm + wm + a * 16 + r0 + r;
                int col = bn + wn + b * 16 + lr;
                Cout[((size_t)z * M_ROWS + row) * NT + col] = acc[a][b][r];
            }
}

// ---------------------------------------------------------------------------
// generic bf16 MFMA NT GEMM (hidden N=64 + small GEMMs)
// 256 threads = 4 waves (2x2), BK=64, reg-staged LDS (+8 u16 pad),
// 2-deep register prefetch.
// EPI 0: f32 store to plane blockIdx.z   EPI 1: bf16 acc + bf16 aux (residual)
// EPI 2: gelu(acc + f32 aux[n]) -> f32/bf16 per OUTF32
// EPI 3: gelu(acc + f32 aux[n]) -> features9 -> FEAT[row][j*512+col]
// ---------------------------------------------------------------------------
template<int BM, int BN, int EPI, bool OUTF32>
__global__ __launch_bounds__(256)
void gemm_mfma(const u16* __restrict__ A, const u16* __restrict__ B,
               void* __restrict__ Cout, const void* __restrict__ aux,
               int M, int N, int Kd, int kPerZ) {
    constexpr int WSM = BM / 2, WSN = BN / 2;
    constexpr int FM = WSM / 16, FN = WSN / 16;
    constexpr int CA = BM / 32, CB = BN / 32;
    __shared__ u16 As[BM][72];
    __shared__ u16 Bs[BN][72];

    const int tid  = threadIdx.x;
    const int wave = tid >> 6, lane = tid & 63;
    const int wm = (wave >> 1) * WSM, wn = (wave & 1) * WSN;
    const int lr = lane & 15, kh = lane >> 4;
    const int bm = blockIdx.y * BM, bn = blockIdx.x * BN;
    const int k0 = blockIdx.z * kPerZ;
    const int nt = kPerZ >> 6;

    const u16* Ab = A + (size_t)bm * Kd + k0;
    const u16* Bb = B + (size_t)bn * Kd + k0;

    f32x4 acc[FM][FN];
#pragma unroll
    for (int a = 0; a < FM; ++a)
#pragma unroll
        for (int b = 0; b < FN; ++b) acc[a][b] = (f32x4){0.f, 0.f, 0.f, 0.f};

    uint4 arA[CA], brA[CB], arB[CA], brB[CB];

#define GLOADT(ar, br, kt)                                                          \
    {                                                                               \
        _Pragma("unroll")                                                           \
        for (int c = 0; c < CA; ++c) {                                              \
            int id = tid + c * 256;                                                 \
            ar[c] = *reinterpret_cast<const uint4*>(Ab + (size_t)(id >> 3) * Kd + (kt) + (id & 7) * 8); \
        }                                                                           \
        _Pragma("unroll")                                                           \
        for (int c = 0; c < CB; ++c) {                                              \
            int id = tid + c * 256;                                                 \
            br[c] = *reinterpret_cast<const uint4*>(Bb + (size_t)(id >> 3) * Kd + (kt) + (id & 7) * 8); \
        }                                                                           \
    }
#define GWRITET(ar, br)                                                             \
    {                                                                               \
        _Pragma("unroll")                                                           \
        for (int c = 0; c < CA; ++c) {                                              \
            int id = tid + c * 256;                                                 \
            *reinterpret_cast<uint4*>(&As[id >> 3][(id & 7) * 8]) = ar[c];          \
        }                                                                           \
        _Pragma("unroll")                                                           \
        for (int c = 0; c < CB; ++c) {                                              \
            int id = tid + c * 256;                                                 \
            *reinterpret_cast<uint4*>(&Bs[id >> 3][(id & 7) * 8]) = br[c];          \
        }                                                                           \
    }
#define GMFMAT()                                                                    \
    {                                                                               \
        _Pragma("unroll")                                                           \
        for (int ks = 0; ks < 2; ++ks) {                                            \
            short8 af[FM], bfr[FN];                                                 \
            _Pragma("unroll")                                                       \
            for (int a = 0; a < FM; ++a)                                            \
                af[a] = *reinterpret_cast<const short8*>(&As[wm + a * 16 + lr][ks * 32 + kh * 8]); \
            _Pragma("unroll")                                                       \
            for (int b = 0; b < FN; ++b)                                            \
                bfr[b] = *reinterpret_cast<const short8*>(&Bs[wn + b * 16 + lr][ks * 32 + kh * 8]); \
            _Pragma("unroll")                                                       \
            for (int a = 0; a < FM; ++a)                                            \
                _Pragma("unroll")                                                   \
                for (int b = 0; b < FN; ++b)                                        \
                    acc[a][b] = __builtin_amdgcn_mfma_f32_16x16x32_bf16(af[a], bfr[b], acc[a][b], 0, 0, 0); \
        }                                                                           \
    }

    GLOADT(arA, brA, 0);
    if (nt > 1) GLOADT(arB, brB, 64);
    int t = 0;
    for (; t + 1 < nt; t += 2) {
        __syncthreads();
        GWRITET(arA, brA);
        __syncthreads();
        if (t + 2 < nt) GLOADT(arA, brA, (t + 2) * 64);
        GMFMAT();
        __syncthreads();
        GWRITET(arB, brB);
        __syncthreads();
        if (t + 3 < nt) GLOADT(arB, brB, (t + 3) * 64);
        GMFMAT();
    }
    if (t < nt) {
        __syncthreads();
        GWRITET(arA, brA);
        __syncthreads();
        GMFMAT();
    }

    const int r0 = kh * 4;   // D: row=(lane>>4)*4+reg, col=lane&15
#pragma unroll
    for (int a = 0; a < FM; ++a) {
#pragma unroll
        for (int b = 0; b < FN; ++b) {
#pragma unroll
            for (int r = 0; r < 4; ++r) {
                int row = bm + wm + a * 16 + r0 + r;
                int col = bn + wn + b * 16 + lr;
                float v = acc[a][b][r];
                if (EPI == 0) {
                    ((float*)Cout)[((size_t)blockIdx.z * M + row) * N + col] = v;
                } else if (EPI == 1) {
                    v += bf2f(((const u16*)aux)[(size_t)row * N + col]);
                    ((u16*)Cout)[(size_t)row * N + col] = f2bf(v);
                } else if (EPI == 2) {
                    v = geluf(v + ((const float*)aux)[col]);
                    if (OUTF32) ((float*)Cout)[(size_t)row * N + col] = v;
                    else        ((u16*)Cout)[(size_t)row * N + col] = f2bf(v);
                } else {  // EPI == 3: gelu -> spline features -> FEAT
                    v = geluf(v + ((const float*)aux)[col]);
                    float f[NFEAT];
                    features9(v, f);
                    u16* o = (u16*)Cout + (size_t)row * (NFEAT * TDIM) + col;
#pragma unroll
                    for (int j = 0; j < NFEAT; ++j) o[j * TDIM] = f2bf(f[j]);
                }
            }
        }
    }
}

// ---------------------------------------------------------------------------
// launch
// ---------------------------------------------------------------------------
extern "C" void kernel_launch(void* const* d_in, const int* in_sizes, int n_in,
                              void* d_out, int out_size, void* d_ws, size_t ws_size,
                              hipStream_t stream) {
    const float* x            = (const float*)d_in[0];
    const float* tm1_ln_w     = (const float*)d_in[1];
    const float* tm1_ln_b     = (const float*)d_in[2];
    const float* tm1_k1_base  = (const float*)d_in[3];
    const float* tm1_k1_spl   = (const float*)d_in[4];
    const float* tm1_k2_base  = (const float*)d_in[5];
    const float* tm1_k2_spl   = (const float*)d_in[6];
    const float* g1_w         = (const float*)d_in[8];
    const float* g1_b         = (const float*)d_in[9];
    const float* k1_base      = (const float*)d_in[10];
    const float* k1_spl       = (const float*)d_in[11];
    const float* tm_ln_w      = (const float*)d_in[12];
    const float* tm_ln_b      = (const float*)d_in[13];
    const float* tm_k1_base   = (const float*)d_in[14];
    const float* tm_k1_spl    = (const float*)d_in[15];
    const float* tm_k2_base   = (const float*)d_in[16];
    const float* tm_k2_spl    = (const float*)d_in[17];
    const float* g2_w         = (const float*)d_in[19];
    const float* g2_b         = (const float*)d_in[20];
    const float* k2_base      = (const float*)d_in[21];
    const float* k2_spl       = (const float*)d_in[22];

    float* out = (float*)d_out;

    // ---- workspace layout -------------------------------------------------
    char* w = (char*)d_ws;
    u16*   FEATA = (u16*)w;   w += (size_t)M_ROWS * 4608 * 2;
    u16*   FEATB = (u16*)w;   w += (size_t)M_ROWS * 4608 * 2;
    u16*   FEAT2 = (u16*)w;   w += (size_t)M_ROWS * 576 * 2;
    float* PART  = (float*)w; w += (size_t)BZ * M_ROWS * 512 * 4;  // also HZ x 2048 x 64
    u16*   XB    = (u16*)w;   w += (size_t)M_ROWS * 512 * 2;
    u16*   BUF1  = (u16*)w;   w += (size_t)M_ROWS * 512 * 2;
    u16*   BUF2  = (u16*)w;   w += (size_t)M_ROWS * 512 * 2;
    u16*   W1a   = (u16*)w;   w += (size_t)64 * 4608 * 2;
    u16*   W1b   = (u16*)w;   w += (size_t)64 * 4608 * 2;
    u16*   W2a   = (u16*)w;   w += (size_t)512 * 576 * 2;
    u16*   W2b   = (u16*)w;   w += (size_t)512 * 576 * 2;
    u16*   WE1   = (u16*)w;   w += (size_t)512 * 512 * 2;
    u16*   WE2   = (u16*)w;   w += (size_t)512 * 512 * 2;
    u16*   KX1   = (u16*)w;   w += (size_t)512 * 4608 * 2;
    u16*   KX2   = (u16*)w;   w += (size_t)512 * 4608 * 2;
    float* LNT   = (float*)w; w += (size_t)4 * 65536 * 4;
    float* SR    = (float*)w; w += 64 * 4;
    const float* LNT0w = LNT, *LNT0b = LNT + 65536;
    const float* LNT2w = LNT + 131072, *LNT2b = LNT + 196608;

    // ---- merged prep (weights, LN transpose, stats zeroing) ---------------
    PrepPtrs p;
    p.g1_w = g1_w; p.g2_w = g2_w;
    p.b1 = tm1_k1_base; p.s1 = tm1_k1_spl;
    p.b2 = tm_k1_base;  p.s2 = tm_k1_spl;
    p.b3 = tm1_k2_base; p.s3 = tm1_k2_spl;
    p.b4 = tm_k2_base;  p.s4 = tm_k2_spl;
    p.b5 = k1_base;     p.s5 = k1_spl;
    p.b6 = k2_base;     p.s6 = k2_spl;
    p.WE1 = WE1; p.WE2 = WE2; p.W1a = W1a; p.W1b = W1b;
    p.W2a = W2a; p.W2b = W2b; p.KX1 = KX1; p.KX2 = KX2;
    p.ln1w = tm1_ln_w; p.ln1b = tm1_ln_b; p.ln2w = tm_ln_w; p.ln2b = tm_ln_b;
    p.LNT = LNT; p.SR = SR;
    prep_all<<<5633, 256, 0, stream>>>(p);

    // ---- branch 1 + branch 2 feature prep ---------------------------------
    stats1_convert<<<1024, 256, 0, stream>>>(x, XB, SR);
    build_feat_dual<<<M_ROWS, 128, 0, stream>>>(x, SR, LNT0w, LNT0b, FEATA, FEATB);

    // ---- branch 1: tm1 = token_mixing(x); y1 = gelu(tm1 @ WE1 + b1) -> out
    gemm_mfma<64, 64, 0, true><<<dim3(1, 32, HZ), 256, 0, stream>>>(FEATA, W1a, PART, nullptr, M_ROWS, 64, 4608, 4608 / HZ);
    build_feat2<<<512, 256, 0, stream>>>(PART, FEAT2);
    gemm_mfma<64, 32, 1, false><<<dim3(16, 32, 1), 256, 0, stream>>>(FEAT2, W2a, BUF1, XB, M_ROWS, 512, 576, 576);
    gemm_mfma<64, 32, 2, true><<<dim3(16, 32, 1), 256, 0, stream>>>(BUF1, WE1, out, g1_b, M_ROWS, 512, 512, 512);

    // ---- branch 2: cm = kan(x); tm = token_mixing(cm); y2; z = kan(y2) ----
    gemm_big<<<256, 512, 0, stream>>>(FEATB, KX1, PART);
    reduce4_bf16_stats<<<1024, 256, 0, stream>>>(PART, BUF2, SR + 32);

    build_feat_ln<<<M_ROWS, 128, 0, stream>>>(BUF2, SR + 32, LNT2w, LNT2b, FEATA);
    gemm_mfma<64, 64, 0, true><<<dim3(1, 32, HZ), 256, 0, stream>>>(FEATA, W1b, PART, nullptr, M_ROWS, 64, 4608, 4608 / HZ);
    build_feat2<<<512, 256, 0, stream>>>(PART, FEAT2);
    gemm_mfma<64, 32, 1, false><<<dim3(16, 32, 1), 256, 0, stream>>>(FEAT2, W2b, BUF1, BUF2, M_ROWS, 512, 576, 576);
    // y2 GEMM: gelu + spline features fused -> FEATB (reused)
    gemm_mfma<64, 32, 3, false><<<dim3(16, 32, 1), 256, 0, stream>>>(BUF1, WE2, FEATB, g2_b, M_ROWS, 512, 512, 512);

    gemm_big<<<256, 512, 0, stream>>>(FEATB, KX2, PART);
    reduce4_add<<<1024, 256, 0, stream>>>(PART, out);
}

// Round 13
// 332.316 us; speedup vs baseline: 1.2343x; 1.0290x over previous
//
#include <hip/hip_runtime.h>
#include <hip/hip_bf16.h>

// Mixer2dTriUKAN forward — bf16 MFMA; fused feature-expansion epilogues,
// dual-output feature builder; big GEMM: 64x128 tile (2 blocks/CU),
// global_load_lds + both-sides-swizzled double-buffered LDS, XCD-tiled grid.
//
// Algebraic simplifications (verified):
//  * sum(softmax(P),-1) == 1  =>  prob_distance/FFT pipeline is dead code.
//  * concat([x,x,x]) @ g_w.T == x @ (sum of the three 512-col blocks).T

#define M_ROWS 2048
#define TDIM   512
#define C4DIM  128
#define NFEAT  9
#define HZ     12      // split-K planes for the N=64 hidden GEMMs
#define BZ     4       // split-K planes for the big GEMMs

typedef unsigned short u16;
typedef __attribute__((ext_vector_type(8))) short short8;
typedef __attribute__((ext_vector_type(4))) float f32x4;

// ---------------------------------------------------------------------------
// helpers
// ---------------------------------------------------------------------------
__device__ __forceinline__ float bf2f(u16 u) {
    union { unsigned int i; float f; } c; c.i = ((unsigned int)u) << 16; return c.f;
}
__device__ __forceinline__ u16 f2bf(float v) {
    __hip_bfloat16 h = __float2bfloat16(v);
    return *reinterpret_cast<u16*>(&h);
}
__device__ __forceinline__ float siluf(float v) { return v / (1.0f + __expf(-v)); }
__device__ __forceinline__ float geluf(float v) {
    return 0.5f * v * (1.0f + erff(v * 0.70710678118654752440f));
}
__device__ __forceinline__ void gload16(const void* g, void* l) {
    __builtin_amdgcn_global_load_lds(
        (const __attribute__((address_space(1))) unsigned int*)g,
        (__attribute__((address_space(3))) unsigned int*)l, 16, 0, 0);
}

// silu + 8 cubic B-spline bases on uniform grid g[i] = (i-3)*0.4 - 1
__device__ __forceinline__ void features9(float v, float* f) {
    f[0] = siluf(v);
    float b[11];
#pragma unroll
    for (int i = 0; i < 11; ++i) {
        float gi  = (float)(i - 3) * 0.4f - 1.0f;
        float gi1 = (float)(i - 2) * 0.4f - 1.0f;
        b[i] = (v >= gi && v < gi1) ? 1.0f : 0.0f;
    }
#pragma unroll
    for (int k = 1; k <= 3; ++k) {
#pragma unroll
        for (int i = 0; i + k < 11; ++i) {
            float gi   = (float)(i - 3) * 0.4f - 1.0f;
            float gi1  = (float)(i - 2) * 0.4f - 1.0f;
            float gik  = (float)(i + k - 3) * 0.4f - 1.0f;
            float gik1 = (float)(i + k - 2) * 0.4f - 1.0f;
            b[i] = (v - gi) * (1.0f / (gik - gi)) * b[i]
                 + (gik1 - v) * (1.0f / (gik1 - gi1)) * b[i + 1];
        }
    }
#pragma unroll
    for (int k = 0; k < 8; ++k) f[1 + k] = b[k];
}

// ---------------------------------------------------------------------------
// merged weight-prep kernel (one launch; block-range dispatch)
// ---------------------------------------------------------------------------
struct PrepPtrs {
    const float *g1_w, *g2_w;
    const float *b1, *s1, *b2, *s2, *b3, *s3, *b4, *s4, *b5, *s5, *b6, *s6;
    u16 *WE1, *WE2, *W1a, *W1b, *W2a, *W2b, *KX1, *KX2;
    const float *ln1w, *ln1b, *ln2w, *ln2b;
    float *LNT;   // 4 * 65536 transposed LN params
    float *SR;    // 64 floats of stats accumulators (zeroed here)
};

__device__ __forceinline__ void wcat_one(const float* bw, const float* sw, u16* out,
                                         int idx, int I) {
    int o = idx / I, i = idx - o * I;
    u16* w = out + (size_t)o * NFEAT * I;
    w[i] = f2bf(bw[idx]);
    const float* sp = sw + (size_t)idx * 8;
#pragma unroll
    for (int k = 0; k < 8; ++k) w[(1 + k) * I + i] = f2bf(sp[k]);
}

__global__ void prep_all(PrepPtrs p) {
    int blk = blockIdx.x, tid = threadIdx.x;
    if (blk < 2048) {                                   // weff x2
        const float* gw = blk < 1024 ? p.g1_w : p.g2_w;
        u16* we = blk < 1024 ? p.WE1 : p.WE2;
        int idx = (blk & 1023) * 256 + tid;
        int o = idx >> 9, i = idx & 511;
        const float* r = gw + (size_t)o * 1536;
        we[idx] = f2bf(r[i] + r[512 + i] + r[1024 + i]);
    } else if (blk < 2560) {                            // 4 small wcat (32768 each)
        int sub = blk - 2048, which = sub >> 7;
        int idx = (sub & 127) * 256 + tid;
        if (which == 0)      wcat_one(p.b1, p.s1, p.W1a, idx, 512);
        else if (which == 1) wcat_one(p.b2, p.s2, p.W1b, idx, 512);
        else if (which == 2) wcat_one(p.b3, p.s3, p.W2a, idx, 64);
        else                 wcat_one(p.b4, p.s4, p.W2b, idx, 64);
    } else if (blk < 4608) {                            // 2 big wcat (262144 each)
        int sub = blk - 2560;
        int idx = (sub & 1023) * 256 + tid;
        if (sub < 1024) wcat_one(p.b5, p.s5, p.KX1, idx, 512);
        else            wcat_one(p.b6, p.s6, p.KX2, idx, 512);
    } else if (blk < 5632) {                            // LN transpose x4
        int sub = blk - 4608, which = sub >> 8;
        const float* src = which == 0 ? p.ln1w : which == 1 ? p.ln1b
                         : which == 2 ? p.ln2w : p.ln2b;
        float* dst = p.LNT + (size_t)which * 65536;
        int idx = (sub & 255) * 256 + tid;              // idx = l*128 + c
        int c = idx & 127, l = idx >> 7;
        dst[c * 512 + l] = src[idx];
    } else {                                            // zero stats accumulators
        if (tid < 64) p.SR[tid] = 0.f;
    }
}

// ---------------------------------------------------------------------------
// stats stage 1 (branch 1): reads x f32, writes bf16 copy, accumulates sums
// ---------------------------------------------------------------------------
__global__ void stats1_convert(const float* __restrict__ X, u16* __restrict__ XB,
                               float* __restrict__ SR) {
    int idx = (blockIdx.x * 256 + threadIdx.x) * 4;
    float4 v = *reinterpret_cast<const float4*>(X + idx);
    ushort4 o; o.x = f2bf(v.x); o.y = f2bf(v.y); o.z = f2bf(v.z); o.w = f2bf(v.w);
    *reinterpret_cast<ushort4*>(XB + idx) = o;
    float s = v.x + v.y + v.z + v.w;
    float q = v.x * v.x + v.y * v.y + v.z * v.z + v.w * v.w;
#pragma unroll
    for (int off = 32; off > 0; off >>= 1) {
        s += __shfl_down(s, off);
        q += __shfl_down(q, off);
    }
    __shared__ float ls[4], lq[4];
    int wv = threadIdx.x >> 6;
    if ((threadIdx.x & 63) == 0) { ls[wv] = s; lq[wv] = q; }
    __syncthreads();
    if (threadIdx.x == 0) {
        s = ls[0] + ls[1] + ls[2] + ls[3];
        q = lq[0] + lq[1] + lq[2] + lq[3];
        int b = (blockIdx.x * 1024) >> 16;   // 64 blocks per batch
        atomicAdd(&SR[b * 2], s);
        atomicAdd(&SR[b * 2 + 1], q);
    }
}

// sum BZ split-K partials -> bf16 cm, and accumulate cm stats (branch 2)
__global__ void reduce4_bf16_stats(const float* __restrict__ P, u16* __restrict__ out,
                                   float* __restrict__ SR) {
    int idx = (blockIdx.x * 256 + threadIdx.x) * 4;
    const size_t PL = (size_t)M_ROWS * 512;
    float4 sv = *reinterpret_cast<const float4*>(P + idx);
#pragma unroll
    for (int z = 1; z < BZ; ++z) {
        float4 t = *reinterpret_cast<const float4*>(P + z * PL + idx);
        sv.x += t.x; sv.y += t.y; sv.z += t.z; sv.w += t.w;
    }
    ushort4 o; o.x = f2bf(sv.x); o.y = f2bf(sv.y); o.z = f2bf(sv.z); o.w = f2bf(sv.w);
    *reinterpret_cast<ushort4*>(out + idx) = o;
    float s = sv.x + sv.y + sv.z + sv.w;
    float q = sv.x * sv.x + sv.y * sv.y + sv.z * sv.z + sv.w * sv.w;
#pragma unroll
    for (int off = 32; off > 0; off >>= 1) {
        s += __shfl_down(s, off);
        q += __shfl_down(q, off);
    }
    __shared__ float ls[4], lq[4];
    int wv = threadIdx.x >> 6;
    if ((threadIdx.x & 63) == 0) { ls[wv] = s; lq[wv] = q; }
    __syncthreads();
    if (threadIdx.x == 0) {
        s = ls[0] + ls[1] + ls[2] + ls[3];
        q = lq[0] + lq[1] + lq[2] + lq[3];
        int b = (blockIdx.x * 1024) >> 16;
        atomicAdd(&SR[b * 2], s);
        atomicAdd(&SR[b * 2 + 1], q);
    }
}

// ---------------------------------------------------------------------------
// feature builders (vectorized x4): 2048 blocks x 128 threads
// ---------------------------------------------------------------------------

// branch1 LN features -> FA, branch2 plain features -> FB (single x read)
__global__ void build_feat_dual(const float* __restrict__ X, const float* __restrict__ SR,
                                const float* __restrict__ lnwT, const float* __restrict__ lnbT,
                                u16* __restrict__ FA, u16* __restrict__ FB) {
    int m = blockIdx.x;
    int i0 = threadIdx.x * 4;
    float4 xv = *reinterpret_cast<const float4*>(X + (size_t)m * TDIM + i0);
    int b = m >> 7, c = m & 127;
    float mu   = SR[b * 2] * (1.0f / 65536.0f);
    float var  = SR[b * 2 + 1] * (1.0f / 65536.0f) - mu * mu;
    float rstd = rsqrtf(var + 1e-5f);
    float4 lw = *reinterpret_cast<const float4*>(lnwT + (size_t)c * 512 + i0);
    float4 lb = *reinterpret_cast<const float4*>(lnbT + (size_t)c * 512 + i0);
    float fb[4][NFEAT], fa[4][NFEAT];
    float xe[4] = {xv.x, xv.y, xv.z, xv.w};
    float lwv[4] = {lw.x, lw.y, lw.z, lw.w};
    float lbv[4] = {lb.x, lb.y, lb.z, lb.w};
#pragma unroll
    for (int e = 0; e < 4; ++e) {
        features9(xe[e], fb[e]);
        features9((xe[e] - mu) * rstd * lwv[e] + lbv[e], fa[e]);
    }
    u16* oa = FA + (size_t)m * (NFEAT * TDIM) + i0;
    u16* ob = FB + (size_t)m * (NFEAT * TDIM) + i0;
#pragma unroll
    for (int j = 0; j < NFEAT; ++j) {
        ushort4 va, vb;
        va.x = f2bf(fa[0][j]); va.y = f2bf(fa[1][j]);
        va.z = f2bf(fa[2][j]); va.w = f2bf(fa[3][j]);
        vb.x = f2bf(fb[0][j]); vb.y = f2bf(fb[1][j]);
        vb.z = f2bf(fb[2][j]); vb.w = f2bf(fb[3][j]);
        *reinterpret_cast<ushort4*>(oa + j * TDIM) = va;
        *reinterpret_cast<ushort4*>(ob + j * TDIM) = vb;
    }
}

// LN features from bf16 input (branch2: cm -> FEAT)
__global__ void build_feat_ln(const u16* __restrict__ X, const float* __restrict__ SR,
                              const float* __restrict__ lnwT, const float* __restrict__ lnbT,
                              u16* __restrict__ FA) {
    int m = blockIdx.x;
    int i0 = threadIdx.x * 4;
    ushort4 xu = *reinterpret_cast<const ushort4*>(X + (size_t)m * TDIM + i0);
    int b = m >> 7, c = m & 127;
    float mu   = SR[b * 2] * (1.0f / 65536.0f);
    float var  = SR[b * 2 + 1] * (1.0f / 65536.0f) - mu * mu;
    float rstd = rsqrtf(var + 1e-5f);
    float4 lw = *reinterpret_cast<const float4*>(lnwT + (size_t)c * 512 + i0);
    float4 lb = *reinterpret_cast<const float4*>(lnbT + (size_t)c * 512 + i0);
    float fa[4][NFEAT];
    float xe[4] = {bf2f(xu.x), bf2f(xu.y), bf2f(xu.z), bf2f(xu.w)};
    float lwv[4] = {lw.x, lw.y, lw.z, lw.w};
    float lbv[4] = {lb.x, lb.y, lb.z, lb.w};
#pragma unroll
    for (int e = 0; e < 4; ++e)
        features9((xe[e] - mu) * rstd * lwv[e] + lbv[e], fa[e]);
    u16* oa = FA + (size_t)m * (NFEAT * TDIM) + i0;
#pragma unroll
    for (int j = 0; j < NFEAT; ++j) {
        ushort4 va;
        va.x = f2bf(fa[0][j]); va.y = f2bf(fa[1][j]);
        va.z = f2bf(fa[2][j]); va.w = f2bf(fa[3][j]);
        *reinterpret_cast<ushort4*>(oa + j * TDIM) = va;
    }
}

// reduce HZ split-K partials (PART[z][m][64] f32) -> h1, then FEAT2[m][j*64+i] bf16
__global__ void build_feat2(const float* __restrict__ PART, u16* __restrict__ FEAT2) {
    int idx = blockIdx.x * blockDim.x + threadIdx.x;  // 2048*64
    int m = idx >> 6, i = idx & 63;
    float h = 0.f;
#pragma unroll
    for (int z = 0; z < HZ; ++z) h += PART[((size_t)z * M_ROWS + m) * 64 + i];
    float f[NFEAT];
    features9(h, f);
    u16* out = FEAT2 + (size_t)m * (NFEAT * 64) + i;
#pragma unroll
    for (int j = 0; j < NFEAT; ++j) out[j * 64] = f2bf(f[j]);
}

// out(f32) += sum of BZ split-K partials
__global__ void reduce4_add(const float* __restrict__ P, float* __restrict__ out) {
    int idx = (blockIdx.x * 256 + threadIdx.x) * 4;
    const size_t PL = (size_t)M_ROWS * 512;
    float4 s = *reinterpret_cast<float4*>(out + idx);
#pragma unroll
    for (int z = 0; z < BZ; ++z) {
        float4 t = *reinterpret_cast<const float4*>(P + z * PL + idx);
        s.x += t.x; s.y += t.y; s.z += t.z; s.w += t.w;
    }
    *reinterpret_cast<float4*>(out + idx) = s;
}

// ---------------------------------------------------------------------------
// BIG GEMM (M=2048, N=512, Kd=4608): 64x128 tile, 512 thr (8 waves, 2m x 4n,
// each wave 32x32), split-K z=BZ=4 (kPerZ=1152, 18 K-steps), grid = 512
// blocks = 2 blocks/CU (cross-block overlap hides barrier drains).
// XCD swizzle: XCD g gets one z-slice x all 4 bn x 16 bm -> 3.5 MB < L2.
// global_load_lds into double-buffered LDS (48 KB); both-sides XOR swizzle.
// ---------------------------------------------------------------------------
__global__ __launch_bounds__(512)
void gemm_big(const u16* __restrict__ A, const u16* __restrict__ B,
              float* __restrict__ Cout) {
    constexpr int Kd = 4608, kPerZ = Kd / BZ, NT = 512;
    constexpr int nt = kPerZ / 64;     // 18
    __shared__ u16 As[2][64][64];
    __shared__ u16 Bs[2][128][64];

    const int lin = blockIdx.x;
    const int sw  = (lin & 7) * 64 + (lin >> 3);   // bijective on [0,512)
    const int bn = (sw & 3) * 128;
    const int bm = ((sw >> 2) & 31) * 64;
    const int z  = sw >> 7;

    const int tid  = threadIdx.x;
    const int wave = tid >> 6, lane = tid & 63;
    const int wm = (wave >> 2) * 32, wn = (wave & 3) * 32;   // 2x4 wave grid
    const int lr = lane & 15, kh = lane >> 4;

    const u16* Ab = A + (size_t)bm * Kd + z * kPerZ;
    const u16* Bb = B + (size_t)bn * Kd + z * kPerZ;

    // staging: 24 chunks of 8 rows (A: 0..7, B: 8..23); 3 chunks per wave.
    // DMA: lane l -> row base + (l>>3), 16B-slot l&7 (linear LDS dest).
    // Pre-swizzled global source so LDS slot s holds k-elems (s^(row&7))*8..
    const int l3  = lane >> 3;
    const int swz = ((lane & 7) ^ l3) * 8;

    f32x4 acc[2][2];
#pragma unroll
    for (int a = 0; a < 2; ++a)
#pragma unroll
        for (int b = 0; b < 2; ++b) acc[a][b] = (f32x4){0.f, 0.f, 0.f, 0.f};

#define BIG_ISSUE(buf, kt)                                                         \
    {                                                                              \
        _Pragma("unroll")                                                          \
        for (int c = 0; c < 3; ++c) {                                              \
            int cc = wave * 3 + c;                                                 \
            if (cc < 8) {                                                          \
                int row = cc * 8 + l3;                                             \
                gload16(Ab + (size_t)row * Kd + (kt) + swz, &As[buf][cc * 8][0]);  \
            } else {                                                               \
                int row = (cc - 8) * 8 + l3;                                       \
                gload16(Bb + (size_t)row * Kd + (kt) + swz, &Bs[buf][(cc - 8) * 8][0]); \
            }                                                                      \
        }                                                                          \
    }

    BIG_ISSUE(0, 0);
    int cur = 0;
    for (int t = 0; t < nt; ++t) {
        __syncthreads();                       // drains vmcnt: buf[cur] ready
        if (t + 1 < nt) BIG_ISSUE(cur ^ 1, (t + 1) * 64);
#pragma unroll
        for (int ks = 0; ks < 2; ++ks) {
            short8 af[2], bfr[2];
#pragma unroll
            for (int a = 0; a < 2; ++a) {
                int row = wm + a * 16 + lr;
                af[a] = *reinterpret_cast<const short8*>(
                    &As[cur][row][((ks * 4 + kh) ^ (lr & 7)) * 8]);
            }
#pragma unroll
            for (int b = 0; b < 2; ++b) {
                int row = wn + b * 16 + lr;
                bfr[b] = *reinterpret_cast<const short8*>(
                    &Bs[cur][row][((ks * 4 + kh) ^ (lr & 7)) * 8]);
            }
#pragma unroll
            for (int a = 0; a < 2; ++a)
#pragma unroll
                for (int b = 0; b < 2; ++b)
                    acc[a][b] = __builtin_amdgcn_mfma_f32_16x16x32_bf16(af[a], bfr[b], acc[a][b], 0, 0, 0);
        }
        cur ^= 1;
    }

    const int r0 = kh * 4;
#pragma unroll
    for (int a = 0; a < 2; ++a)
#pragma unroll
        for (int b = 0; b < 2; ++b)
#pragma unroll
            for (int r = 0; r < 4; ++r) {
                int row = bm + wm + a * 16 + r0 + r;
                int col = bn + wn + b * 16 + lr;
                Cout[((size_t)z * M_ROWS + row) * NT + col] = acc[a][b][r];
            }
}

// ---------------------------------------------------------------------------
// generic bf16 MFMA NT GEMM (hidden N=64 + small GEMMs)
// 256 threads = 4 waves (2x2), BK=64, reg-staged LDS (+8 u16 pad),
// 2-deep register prefetch.
// EPI 0: f32 store to plane blockIdx.z   EPI 1: bf16 acc + bf16 aux (residual)
// EPI 2: gelu(acc + f32 aux[n]) -> f32/bf16 per OUTF32
// EPI 3: gelu(acc + f32 aux[n]) -> features9 -> FEAT[row][j*512+col]
// ---------------------------------------------------------------------------
template<int BM, int BN, int EPI, bool OUTF32>
__global__ __launch_bounds__(256)
void gemm_mfma(const u16* __restrict__ A, const u16* __restrict__ B,
               void* __restrict__ Cout, const void* __restrict__ aux,
               int M, int N, int Kd, int kPerZ) {
    constexpr int WSM = BM / 2, WSN = BN / 2;
    constexpr int FM = WSM / 16, FN = WSN / 16;
    constexpr int CA = BM / 32, CB = BN / 32;
    __shared__ u16 As[BM][72];
    __shared__ u16 Bs[BN][72];

    const int tid  = threadIdx.x;
    const int wave = tid >> 6, lane = tid & 63;
    const int wm = (wave >> 1) * WSM, wn = (wave & 1) * WSN;
    const int lr = lane & 15, kh = lane >> 4;
    const int bm = blockIdx.y * BM, bn = blockIdx.x * BN;
    const int k0 = blockIdx.z * kPerZ;
    const int nt = kPerZ >> 6;

    const u16* Ab = A + (size_t)bm * Kd + k0;
    const u16* Bb = B + (size_t)bn * Kd + k0;

    f32x4 acc[FM][FN];
#pragma unroll
    for (int a = 0; a < FM; ++a)
#pragma unroll
        for (int b = 0; b < FN; ++b) acc[a][b] = (f32x4){0.f, 0.f, 0.f, 0.f};

    uint4 arA[CA], brA[CB], arB[CA], brB[CB];

#define GLOADT(ar, br, kt)                                                          \
    {                                                                               \
        _Pragma("unroll")                                                           \
        for (int c = 0; c < CA; ++c) {                                              \
            int id = tid + c * 256;                                                 \
            ar[c] = *reinterpret_cast<const uint4*>(Ab + (size_t)(id >> 3) * Kd + (kt) + (id & 7) * 8); \
        }                                                                           \
        _Pragma("unroll")                                                           \
        for (int c = 0; c < CB; ++c) {                                              \
            int id = tid + c * 256;                                                 \
            br[c] = *reinterpret_cast<const uint4*>(Bb + (size_t)(id >> 3) * Kd + (kt) + (id & 7) * 8); \
        }                                                                           \
    }
#define GWRITET(ar, br)                                                             \
    {                                                                               \
        _Pragma("unroll")                                                           \
        for (int c = 0; c < CA; ++c) {                                              \
            int id = tid + c * 256;                                                 \
            *reinterpret_cast<uint4*>(&As[id >> 3][(id & 7) * 8]) = ar[c];          \
        }                                                                           \
        _Pragma("unroll")                                                           \
        for (int c = 0; c < CB; ++c) {                                              \
            int id = tid + c * 256;                                                 \
            *reinterpret_cast<uint4*>(&Bs[id >> 3][(id & 7) * 8]) = br[c];          \
        }                                                                           \
    }
#define GMFMAT()                                                                    \
    {                                                                               \
        _Pragma("unroll")                                                           \
        for (int ks = 0; ks < 2; ++ks) {                                            \
            short8 af[FM], bfr[FN];                                                 \
            _Pragma("unroll")                                                       \
            for (int a = 0; a < FM; ++a)                                            \
                af[a] = *reinterpret_cast<const short8*>(&As[wm + a * 16 + lr][ks * 32 + kh * 8]); \
            _Pragma("unroll")                                                       \
            for (int b = 0; b < FN; ++b)                                            \
                bfr[b] = *reinterpret_cast<const short8*>(&Bs[wn + b * 16 + lr][ks * 32 + kh * 8]); \
            _Pragma("unroll")                                                       \
            for (int a = 0; a < FM; ++a)                                            \
                _Pragma("unroll")                                                   \
                for (int b = 0; b < FN; ++b)                                        \
                    acc[a][b] = __builtin_amdgcn_mfma_f32_16x16x32_bf16(af[a], bfr[b], acc[a][b], 0, 0, 0); \
        }                                                                           \
    }

    GLOADT(arA, brA, 0);
    if (nt > 1) GLOADT(arB, brB, 64);
    int t = 0;
    for (; t + 1 < nt; t += 2) {
        __syncthreads();
        GWRITET(arA, brA);
        __syncthreads();
        if (t + 2 < nt) GLOADT(arA, brA, (t + 2) * 64);
        GMFMAT();
        __syncthreads();
        GWRITET(arB, brB);
        __syncthreads();
        if (t + 3 < nt) GLOADT(arB, brB, (t + 3) * 64);
        GMFMAT();
    }
    if (t < nt) {
        __syncthreads();
        GWRITET(arA, brA);
        __syncthreads();
        GMFMAT();
    }

    const int r0 = kh * 4;   // D: row=(lane>>4)*4+reg, col=lane&15
#pragma unroll
    for (int a = 0; a < FM; ++a) {
#pragma unroll
        for (int b = 0; b < FN; ++b) {
#pragma unroll
            for (int r = 0; r < 4; ++r) {
                int row = bm + wm + a * 16 + r0 + r;
                int col = bn + wn + b * 16 + lr;
                float v = acc[a][b][r];
                if (EPI == 0) {
                    ((float*)Cout)[((size_t)blockIdx.z * M + row) * N + col] = v;
                } else if (EPI == 1) {
                    v += bf2f(((const u16*)aux)[(size_t)row * N + col]);
                    ((u16*)Cout)[(size_t)row * N + col] = f2bf(v);
                } else if (EPI == 2) {
                    v = geluf(v + ((const float*)aux)[col]);
                    if (OUTF32) ((float*)Cout)[(size_t)row * N + col] = v;
                    else        ((u16*)Cout)[(size_t)row * N + col] = f2bf(v);
                } else {  // EPI == 3: gelu -> spline features -> FEAT
                    v = geluf(v + ((const float*)aux)[col]);
                    float f[NFEAT];
                    features9(v, f);
                    u16* o = (u16*)Cout + (size_t)row * (NFEAT * TDIM) + col;
#pragma unroll
                    for (int j = 0; j < NFEAT; ++j) o[j * TDIM] = f2bf(f[j]);
                }
            }
        }
    }
}

// ---------------------------------------------------------------------------
// launch
// ---------------------------------------------------------------------------
extern "C" void kernel_launch(void* const* d_in, const int* in_sizes, int n_in,
                              void* d_out, int out_size, void* d_ws, size_t ws_size,
                              hipStream_t stream) {
    const float* x            = (const float*)d_in[0];
    const float* tm1_ln_w     = (const float*)d_in[1];
    const float* tm1_ln_b     = (const float*)d_in[2];
    const float* tm1_k1_base  = (const float*)d_in[3];
    const float* tm1_k1_spl   = (const float*)d_in[4];
    const float* tm1_k2_base  = (const float*)d_in[5];
    const float* tm1_k2_spl   = (const float*)d_in[6];
    const float* g1_w         = (const float*)d_in[8];
    const float* g1_b         = (const float*)d_in[9];
    const float* k1_base      = (const float*)d_in[10];
    const float* k1_spl       = (const float*)d_in[11];
    const float* tm_ln_w      = (const float*)d_in[12];
    const float* tm_ln_b      = (const float*)d_in[13];
    const float* tm_k1_base   = (const float*)d_in[14];
    const float* tm_k1_spl    = (const float*)d_in[15];
    const float* tm_k2_base   = (const float*)d_in[16];
    const float* tm_k2_spl    = (const float*)d_in[17];
    const float* g2_w         = (const float*)d_in[19];
    const float* g2_b         = (const float*)d_in[20];
    const float* k2_base      = (const float*)d_in[21];
    const float* k2_spl       = (const float*)d_in[22];

    float* out = (float*)d_out;

    // ---- workspace layout -------------------------------------------------
    char* w = (char*)d_ws;
    u16*   FEATA = (u16*)w;   w += (size_t)M_ROWS * 4608 * 2;
    u16*   FEATB = (u16*)w;   w += (size_t)M_ROWS * 4608 * 2;
    u16*   FEAT2 = (u16*)w;   w += (size_t)M_ROWS * 576 * 2;
    float* PART  = (float*)w; w += (size_t)BZ * M_ROWS * 512 * 4;  // also HZ x 2048 x 64
    u16*   XB    = (u16*)w;   w += (size_t)M_ROWS * 512 * 2;
    u16*   BUF1  = (u16*)w;   w += (size_t)M_ROWS * 512 * 2;
    u16*   BUF2  = (u16*)w;   w += (size_t)M_ROWS * 512 * 2;
    u16*   W1a   = (u16*)w;   w += (size_t)64 * 4608 * 2;
    u16*   W1b   = (u16*)w;   w += (size_t)64 * 4608 * 2;
    u16*   W2a   = (u16*)w;   w += (size_t)512 * 576 * 2;
    u16*   W2b   = (u16*)w;   w += (size_t)512 * 576 * 2;
    u16*   WE1   = (u16*)w;   w += (size_t)512 * 512 * 2;
    u16*   WE2   = (u16*)w;   w += (size_t)512 * 512 * 2;
    u16*   KX1   = (u16*)w;   w += (size_t)512 * 4608 * 2;
    u16*   KX2   = (u16*)w;   w += (size_t)512 * 4608 * 2;
    float* LNT   = (float*)w; w += (size_t)4 * 65536 * 4;
    float* SR    = (float*)w; w += 64 * 4;
    const float* LNT0w = LNT, *LNT0b = LNT + 65536;
    const float* LNT2w = LNT + 131072, *LNT2b = LNT + 196608;

    // ---- merged prep (weights, LN transpose, stats zeroing) ---------------
    PrepPtrs p;
    p.g1_w = g1_w; p.g2_w = g2_w;
    p.b1 = tm1_k1_base; p.s1 = tm1_k1_spl;
    p.b2 = tm_k1_base;  p.s2 = tm_k1_spl;
    p.b3 = tm1_k2_base; p.s3 = tm1_k2_spl;
    p.b4 = tm_k2_base;  p.s4 = tm_k2_spl;
    p.b5 = k1_base;     p.s5 = k1_spl;
    p.b6 = k2_base;     p.s6 = k2_spl;
    p.WE1 = WE1; p.WE2 = WE2; p.W1a = W1a; p.W1b = W1b;
    p.W2a = W2a; p.W2b = W2b; p.KX1 = KX1; p.KX2 = KX2;
    p.ln1w = tm1_ln_w; p.ln1b = tm1_ln_b; p.ln2w = tm_ln_w; p.ln2b = tm_ln_b;
    p.LNT = LNT; p.SR = SR;
    prep_all<<<5633, 256, 0, stream>>>(p);

    // ---- branch 1 + branch 2 feature prep ---------------------------------
    stats1_convert<<<1024, 256, 0, stream>>>(x, XB, SR);
    build_feat_dual<<<M_ROWS, 128, 0, stream>>>(x, SR, LNT0w, LNT0b, FEATA, FEATB);

    // ---- branch 1: tm1 = token_mixing(x); y1 = gelu(tm1 @ WE1 + b1) -> out
    gemm_mfma<64, 64, 0, true><<<dim3(1, 32, HZ), 256, 0, stream>>>(FEATA, W1a, PART, nullptr, M_ROWS, 64, 4608, 4608 / HZ);
    build_feat2<<<512, 256, 0, stream>>>(PART, FEAT2);
    gemm_mfma<64, 32, 1, false><<<dim3(16, 32, 1), 256, 0, stream>>>(FEAT2, W2a, BUF1, XB, M_ROWS, 512, 576, 576);
    gemm_mfma<64, 32, 2, true><<<dim3(16, 32, 1), 256, 0, stream>>>(BUF1, WE1, out, g1_b, M_ROWS, 512, 512, 512);

    // ---- branch 2: cm = kan(x); tm = token_mixing(cm); y2; z = kan(y2) ----
    gemm_big<<<512, 512, 0, stream>>>(FEATB, KX1, PART);
    reduce4_bf16_stats<<<1024, 256, 0, stream>>>(PART, BUF2, SR + 32);

    build_feat_ln<<<M_ROWS, 128, 0, stream>>>(BUF2, SR + 32, LNT2w, LNT2b, FEATA);
    gemm_mfma<64, 64, 0, true><<<dim3(1, 32, HZ), 256, 0, stream>>>(FEATA, W1b, PART, nullptr, M_ROWS, 64, 4608, 4608 / HZ);
    build_feat2<<<512, 256, 0, stream>>>(PART, FEAT2);
    gemm_mfma<64, 32, 1, false><<<dim3(16, 32, 1), 256, 0, stream>>>(FEAT2, W2b, BUF1, BUF2, M_ROWS, 512, 576, 576);
    // y2 GEMM: gelu + spline features fused -> FEATB (reused)
    gemm_mfma<64, 32, 3, false><<<dim3(16, 32, 1), 256, 0, stream>>>(BUF1, WE2, FEATB, g2_b, M_ROWS, 512, 512, 512);

    gemm_big<<<512, 512, 0, stream>>>(FEATB, KX2, PART);
    reduce4_add<<<1024, 256, 0, stream>>>(PART, out);
}

// Round 14
// 278.644 us; speedup vs baseline: 1.4721x; 1.1926x over previous
//
#include <hip/hip_runtime.h>
#include <hip/hip_bf16.h>

// Mixer2dTriUKAN forward — bf16 MFMA; ALL GEMMs now use global_load_lds +
// both-sides-swizzled double-buffered LDS (proven structure), fused
// feature-expansion epilogues, dual-output feature builder.
//
// Algebraic simplifications (verified):
//  * sum(softmax(P),-1) == 1  =>  prob_distance/FFT pipeline is dead code.
//  * concat([x,x,x]) @ g_w.T == x @ (sum of the three 512-col blocks).T

#define M_ROWS 2048
#define TDIM   512
#define C4DIM  128
#define NFEAT  9
#define HZ     12      // split-K planes for the N=64 hidden GEMMs
#define BZ     4       // split-K planes for the big GEMMs

typedef unsigned short u16;
typedef __attribute__((ext_vector_type(8))) short short8;
typedef __attribute__((ext_vector_type(4))) float f32x4;

// ---------------------------------------------------------------------------
// helpers
// ---------------------------------------------------------------------------
__device__ __forceinline__ float bf2f(u16 u) {
    union { unsigned int i; float f; } c; c.i = ((unsigned int)u) << 16; return c.f;
}
__device__ __forceinline__ u16 f2bf(float v) {
    __hip_bfloat16 h = __float2bfloat16(v);
    return *reinterpret_cast<u16*>(&h);
}
__device__ __forceinline__ float siluf(float v) { return v / (1.0f + __expf(-v)); }
__device__ __forceinline__ float geluf(float v) {
    return 0.5f * v * (1.0f + erff(v * 0.70710678118654752440f));
}
__device__ __forceinline__ void gload16(const void* g, void* l) {
    __builtin_amdgcn_global_load_lds(
        (const __attribute__((address_space(1))) unsigned int*)g,
        (__attribute__((address_space(3))) unsigned int*)l, 16, 0, 0);
}

// silu + 8 cubic B-spline bases on uniform grid g[i] = (i-3)*0.4 - 1
__device__ __forceinline__ void features9(float v, float* f) {
    f[0] = siluf(v);
    float b[11];
#pragma unroll
    for (int i = 0; i < 11; ++i) {
        float gi  = (float)(i - 3) * 0.4f - 1.0f;
        float gi1 = (float)(i - 2) * 0.4f - 1.0f;
        b[i] = (v >= gi && v < gi1) ? 1.0f : 0.0f;
    }
#pragma unroll
    for (int k = 1; k <= 3; ++k) {
#pragma unroll
        for (int i = 0; i + k < 11; ++i) {
            float gi   = (float)(i - 3) * 0.4f - 1.0f;
            float gi1  = (float)(i - 2) * 0.4f - 1.0f;
            float gik  = (float)(i + k - 3) * 0.4f - 1.0f;
            float gik1 = (float)(i + k - 2) * 0.4f - 1.0f;
            b[i] = (v - gi) * (1.0f / (gik - gi)) * b[i]
                 + (gik1 - v) * (1.0f / (gik1 - gi1)) * b[i + 1];
        }
    }
#pragma unroll
    for (int k = 0; k < 8; ++k) f[1 + k] = b[k];
}

// ---------------------------------------------------------------------------
// merged weight-prep kernel (one launch; block-range dispatch)
// ---------------------------------------------------------------------------
struct PrepPtrs {
    const float *g1_w, *g2_w;
    const float *b1, *s1, *b2, *s2, *b3, *s3, *b4, *s4, *b5, *s5, *b6, *s6;
    u16 *WE1, *WE2, *W1a, *W1b, *W2a, *W2b, *KX1, *KX2;
    const float *ln1w, *ln1b, *ln2w, *ln2b;
    float *LNT;   // 4 * 65536 transposed LN params
    float *SR;    // 64 floats of stats accumulators (zeroed here)
};

__device__ __forceinline__ void wcat_one(const float* bw, const float* sw, u16* out,
                                         int idx, int I) {
    int o = idx / I, i = idx - o * I;
    u16* w = out + (size_t)o * NFEAT * I;
    w[i] = f2bf(bw[idx]);
    const float* sp = sw + (size_t)idx * 8;
#pragma unroll
    for (int k = 0; k < 8; ++k) w[(1 + k) * I + i] = f2bf(sp[k]);
}

__global__ void prep_all(PrepPtrs p) {
    int blk = blockIdx.x, tid = threadIdx.x;
    if (blk < 2048) {                                   // weff x2
        const float* gw = blk < 1024 ? p.g1_w : p.g2_w;
        u16* we = blk < 1024 ? p.WE1 : p.WE2;
        int idx = (blk & 1023) * 256 + tid;
        int o = idx >> 9, i = idx & 511;
        const float* r = gw + (size_t)o * 1536;
        we[idx] = f2bf(r[i] + r[512 + i] + r[1024 + i]);
    } else if (blk < 2560) {                            // 4 small wcat (32768 each)
        int sub = blk - 2048, which = sub >> 7;
        int idx = (sub & 127) * 256 + tid;
        if (which == 0)      wcat_one(p.b1, p.s1, p.W1a, idx, 512);
        else if (which == 1) wcat_one(p.b2, p.s2, p.W1b, idx, 512);
        else if (which == 2) wcat_one(p.b3, p.s3, p.W2a, idx, 64);
        else                 wcat_one(p.b4, p.s4, p.W2b, idx, 64);
    } else if (blk < 4608) {                            // 2 big wcat (262144 each)
        int sub = blk - 2560;
        int idx = (sub & 1023) * 256 + tid;
        if (sub < 1024) wcat_one(p.b5, p.s5, p.KX1, idx, 512);
        else            wcat_one(p.b6, p.s6, p.KX2, idx, 512);
    } else if (blk < 5632) {                            // LN transpose x4
        int sub = blk - 4608, which = sub >> 8;
        const float* src = which == 0 ? p.ln1w : which == 1 ? p.ln1b
                         : which == 2 ? p.ln2w : p.ln2b;
        float* dst = p.LNT + (size_t)which * 65536;
        int idx = (sub & 255) * 256 + tid;              // idx = l*128 + c
        int c = idx & 127, l = idx >> 7;
        dst[c * 512 + l] = src[idx];
    } else {                                            // zero stats accumulators
        if (tid < 64) p.SR[tid] = 0.f;
    }
}

// ---------------------------------------------------------------------------
// stats stage 1 (branch 1): reads x f32, writes bf16 copy, accumulates sums
// ---------------------------------------------------------------------------
__global__ void stats1_convert(const float* __restrict__ X, u16* __restrict__ XB,
                               float* __restrict__ SR) {
    int idx = (blockIdx.x * 256 + threadIdx.x) * 4;
    float4 v = *reinterpret_cast<const float4*>(X + idx);
    ushort4 o; o.x = f2bf(v.x); o.y = f2bf(v.y); o.z = f2bf(v.z); o.w = f2bf(v.w);
    *reinterpret_cast<ushort4*>(XB + idx) = o;
    float s = v.x + v.y + v.z + v.w;
    float q = v.x * v.x + v.y * v.y + v.z * v.z + v.w * v.w;
#pragma unroll
    for (int off = 32; off > 0; off >>= 1) {
        s += __shfl_down(s, off);
        q += __shfl_down(q, off);
    }
    __shared__ float ls[4], lq[4];
    int wv = threadIdx.x >> 6;
    if ((threadIdx.x & 63) == 0) { ls[wv] = s; lq[wv] = q; }
    __syncthreads();
    if (threadIdx.x == 0) {
        s = ls[0] + ls[1] + ls[2] + ls[3];
        q = lq[0] + lq[1] + lq[2] + lq[3];
        int b = (blockIdx.x * 1024) >> 16;   // 64 blocks per batch
        atomicAdd(&SR[b * 2], s);
        atomicAdd(&SR[b * 2 + 1], q);
    }
}

// sum BZ split-K partials -> bf16 cm, and accumulate cm stats (branch 2)
__global__ void reduce4_bf16_stats(const float* __restrict__ P, u16* __restrict__ out,
                                   float* __restrict__ SR) {
    int idx = (blockIdx.x * 256 + threadIdx.x) * 4;
    const size_t PL = (size_t)M_ROWS * 512;
    float4 sv = *reinterpret_cast<const float4*>(P + idx);
#pragma unroll
    for (int z = 1; z < BZ; ++z) {
        float4 t = *reinterpret_cast<const float4*>(P + z * PL + idx);
        sv.x += t.x; sv.y += t.y; sv.z += t.z; sv.w += t.w;
    }
    ushort4 o; o.x = f2bf(sv.x); o.y = f2bf(sv.y); o.z = f2bf(sv.z); o.w = f2bf(sv.w);
    *reinterpret_cast<ushort4*>(out + idx) = o;
    float s = sv.x + sv.y + sv.z + sv.w;
    float q = sv.x * sv.x + sv.y * sv.y + sv.z * sv.z + sv.w * sv.w;
#pragma unroll
    for (int off = 32; off > 0; off >>= 1) {
        s += __shfl_down(s, off);
        q += __shfl_down(q, off);
    }
    __shared__ float ls[4], lq[4];
    int wv = threadIdx.x >> 6;
    if ((threadIdx.x & 63) == 0) { ls[wv] = s; lq[wv] = q; }
    __syncthreads();
    if (threadIdx.x == 0) {
        s = ls[0] + ls[1] + ls[2] + ls[3];
        q = lq[0] + lq[1] + lq[2] + lq[3];
        int b = (blockIdx.x * 1024) >> 16;
        atomicAdd(&SR[b * 2], s);
        atomicAdd(&SR[b * 2 + 1], q);
    }
}

// ---------------------------------------------------------------------------
// feature builders (vectorized x4): 2048 blocks x 128 threads
// ---------------------------------------------------------------------------

// branch1 LN features -> FA, branch2 plain features -> FB (single x read)
__global__ void build_feat_dual(const float* __restrict__ X, const float* __restrict__ SR,
                                const float* __restrict__ lnwT, const float* __restrict__ lnbT,
                                u16* __restrict__ FA, u16* __restrict__ FB) {
    int m = blockIdx.x;
    int i0 = threadIdx.x * 4;
    float4 xv = *reinterpret_cast<const float4*>(X + (size_t)m * TDIM + i0);
    int b = m >> 7, c = m & 127;
    float mu   = SR[b * 2] * (1.0f / 65536.0f);
    float var  = SR[b * 2 + 1] * (1.0f / 65536.0f) - mu * mu;
    float rstd = rsqrtf(var + 1e-5f);
    float4 lw = *reinterpret_cast<const float4*>(lnwT + (size_t)c * 512 + i0);
    float4 lb = *reinterpret_cast<const float4*>(lnbT + (size_t)c * 512 + i0);
    float fb[4][NFEAT], fa[4][NFEAT];
    float xe[4] = {xv.x, xv.y, xv.z, xv.w};
    float lwv[4] = {lw.x, lw.y, lw.z, lw.w};
    float lbv[4] = {lb.x, lb.y, lb.z, lb.w};
#pragma unroll
    for (int e = 0; e < 4; ++e) {
        features9(xe[e], fb[e]);
        features9((xe[e] - mu) * rstd * lwv[e] + lbv[e], fa[e]);
    }
    u16* oa = FA + (size_t)m * (NFEAT * TDIM) + i0;
    u16* ob = FB + (size_t)m * (NFEAT * TDIM) + i0;
#pragma unroll
    for (int j = 0; j < NFEAT; ++j) {
        ushort4 va, vb;
        va.x = f2bf(fa[0][j]); va.y = f2bf(fa[1][j]);
        va.z = f2bf(fa[2][j]); va.w = f2bf(fa[3][j]);
        vb.x = f2bf(fb[0][j]); vb.y = f2bf(fb[1][j]);
        vb.z = f2bf(fb[2][j]); vb.w = f2bf(fb[3][j]);
        *reinterpret_cast<ushort4*>(oa + j * TDIM) = va;
        *reinterpret_cast<ushort4*>(ob + j * TDIM) = vb;
    }
}

// LN features from bf16 input (branch2: cm -> FEAT)
__global__ void build_feat_ln(const u16* __restrict__ X, const float* __restrict__ SR,
                              const float* __restrict__ lnwT, const float* __restrict__ lnbT,
                              u16* __restrict__ FA) {
    int m = blockIdx.x;
    int i0 = threadIdx.x * 4;
    ushort4 xu = *reinterpret_cast<const ushort4*>(X + (size_t)m * TDIM + i0);
    int b = m >> 7, c = m & 127;
    float mu   = SR[b * 2] * (1.0f / 65536.0f);
    float var  = SR[b * 2 + 1] * (1.0f / 65536.0f) - mu * mu;
    float rstd = rsqrtf(var + 1e-5f);
    float4 lw = *reinterpret_cast<const float4*>(lnwT + (size_t)c * 512 + i0);
    float4 lb = *reinterpret_cast<const float4*>(lnbT + (size_t)c * 512 + i0);
    float fa[4][NFEAT];
    float xe[4] = {bf2f(xu.x), bf2f(xu.y), bf2f(xu.z), bf2f(xu.w)};
    float lwv[4] = {lw.x, lw.y, lw.z, lw.w};
    float lbv[4] = {lb.x, lb.y, lb.z, lb.w};
#pragma unroll
    for (int e = 0; e < 4; ++e)
        features9((xe[e] - mu) * rstd * lwv[e] + lbv[e], fa[e]);
    u16* oa = FA + (size_t)m * (NFEAT * TDIM) + i0;
#pragma unroll
    for (int j = 0; j < NFEAT; ++j) {
        ushort4 va;
        va.x = f2bf(fa[0][j]); va.y = f2bf(fa[1][j]);
        va.z = f2bf(fa[2][j]); va.w = f2bf(fa[3][j]);
        *reinterpret_cast<ushort4*>(oa + j * TDIM) = va;
    }
}

// reduce HZ split-K partials (PART[z][m][64] f32) -> h1, then FEAT2[m][j*64+i] bf16
__global__ void build_feat2(const float* __restrict__ PART, u16* __restrict__ FEAT2) {
    int idx = blockIdx.x * blockDim.x + threadIdx.x;  // 2048*64
    int m = idx >> 6, i = idx & 63;
    float h = 0.f;
#pragma unroll
    for (int z = 0; z < HZ; ++z) h += PART[((size_t)z * M_ROWS + m) * 64 + i];
    float f[NFEAT];
    features9(h, f);
    u16* out = FEAT2 + (size_t)m * (NFEAT * 64) + i;
#pragma unroll
    for (int j = 0; j < NFEAT; ++j) out[j * 64] = f2bf(f[j]);
}

// out(f32) += sum of BZ split-K partials
__global__ void reduce4_add(const float* __restrict__ P, float* __restrict__ out) {
    int idx = (blockIdx.x * 256 + threadIdx.x) * 4;
    const size_t PL = (size_t)M_ROWS * 512;
    float4 s = *reinterpret_cast<float4*>(out + idx);
#pragma unroll
    for (int z = 0; z < BZ; ++z) {
        float4 t = *reinterpret_cast<const float4*>(P + z * PL + idx);
        s.x += t.x; s.y += t.y; s.z += t.z; s.w += t.w;
    }
    *reinterpret_cast<float4*>(out + idx) = s;
}

// ---------------------------------------------------------------------------
// BIG GEMM (M=2048, N=512, Kd=4608): 64x128 tile, 512 thr (8 waves, 2m x 4n,
// each wave 32x32), split-K z=BZ=4 (kPerZ=1152, 18 K-steps), grid = 512
// blocks = 2 blocks/CU. XCD swizzle: XCD g gets one z-slice x all tiles.
// global_load_lds into double-buffered LDS (48 KB); both-sides XOR swizzle.
// ---------------------------------------------------------------------------
__global__ __launch_bounds__(512)
void gemm_big(const u16* __restrict__ A, const u16* __restrict__ B,
              float* __restrict__ Cout) {
    constexpr int Kd = 4608, kPerZ = Kd / BZ, NT = 512;
    constexpr int nt = kPerZ / 64;     // 18
    __shared__ u16 As[2][64][64];
    __shared__ u16 Bs[2][128][64];

    const int lin = blockIdx.x;
    const int sw  = (lin & 7) * 64 + (lin >> 3);   // bijective on [0,512)
    const int bn = (sw & 3) * 128;
    const int bm = ((sw >> 2) & 31) * 64;
    const int z  = sw >> 7;

    const int tid  = threadIdx.x;
    const int wave = tid >> 6, lane = tid & 63;
    const int wm = (wave >> 2) * 32, wn = (wave & 3) * 32;   // 2x4 wave grid
    const int lr = lane & 15, kh = lane >> 4;

    const u16* Ab = A + (size_t)bm * Kd + z * kPerZ;
    const u16* Bb = B + (size_t)bn * Kd + z * kPerZ;

    const int l3  = lane >> 3;
    const int swz = ((lane & 7) ^ l3) * 8;

    f32x4 acc[2][2];
#pragma unroll
    for (int a = 0; a < 2; ++a)
#pragma unroll
        for (int b = 0; b < 2; ++b) acc[a][b] = (f32x4){0.f, 0.f, 0.f, 0.f};

#define BIG_ISSUE(buf, kt)                                                         \
    {                                                                              \
        _Pragma("unroll")                                                          \
        for (int c = 0; c < 3; ++c) {                                              \
            int cc = wave * 3 + c;                                                 \
            if (cc < 8) {                                                          \
                int row = cc * 8 + l3;                                             \
                gload16(Ab + (size_t)row * Kd + (kt) + swz, &As[buf][cc * 8][0]);  \
            } else {                                                               \
                int row = (cc - 8) * 8 + l3;                                       \
                gload16(Bb + (size_t)row * Kd + (kt) + swz, &Bs[buf][(cc - 8) * 8][0]); \
            }                                                                      \
        }                                                                          \
    }

    BIG_ISSUE(0, 0);
    int cur = 0;
    for (int t = 0; t < nt; ++t) {
        __syncthreads();                       // drains vmcnt: buf[cur] ready
        if (t + 1 < nt) BIG_ISSUE(cur ^ 1, (t + 1) * 64);
#pragma unroll
        for (int ks = 0; ks < 2; ++ks) {
            short8 af[2], bfr[2];
#pragma unroll
            for (int a = 0; a < 2; ++a) {
                int row = wm + a * 16 + lr;
                af[a] = *reinterpret_cast<const short8*>(
                    &As[cur][row][((ks * 4 + kh) ^ (lr & 7)) * 8]);
            }
#pragma unroll
            for (int b = 0; b < 2; ++b) {
                int row = wn + b * 16 + lr;
                bfr[b] = *reinterpret_cast<const short8*>(
                    &Bs[cur][row][((ks * 4 + kh) ^ (lr & 7)) * 8]);
            }
#pragma unroll
            for (int a = 0; a < 2; ++a)
#pragma unroll
                for (int b = 0; b < 2; ++b)
                    acc[a][b] = __builtin_amdgcn_mfma_f32_16x16x32_bf16(af[a], bfr[b], acc[a][b], 0, 0, 0);
        }
        cur ^= 1;
    }

    const int r0 = kh * 4;
#pragma unroll
    for (int a = 0; a < 2; ++a)
#pragma unroll
        for (int b = 0; b < 2; ++b)
#pragma unroll
            for (int r = 0; r < 4; ++r) {
                int row = bm + wm + a * 16 + r0 + r;
                int col = bn + wn + b * 16 + lr;
                Cout[((size_t)z * M_ROWS + row) * NT + col] = acc[a][b][r];
            }
}

// ---------------------------------------------------------------------------
// generic DMA-staged bf16 MFMA NT GEMM (hidden N=64 + small GEMMs)
// 256 threads = 4 waves (2x2, each 32 x BN/2), double-buffered LDS via
// global_load_lds, both-sides XOR swizzle, one barrier per K-step.
// EPI 0: f32 store to plane blockIdx.z   EPI 1: bf16 acc + bf16 aux (residual)
// EPI 2: gelu(acc + f32 aux[n]) -> f32/bf16 per OUTF32
// EPI 3: gelu(acc + f32 aux[n]) -> features9 -> FEAT[row][j*512+col]
// ---------------------------------------------------------------------------
template<int BM, int BN, int EPI, bool OUTF32>
__global__ __launch_bounds__(256)
void gemm_dma(const u16* __restrict__ A, const u16* __restrict__ B,
              void* __restrict__ Cout, const void* __restrict__ aux,
              int M, int N, int Kd, int kPerZ) {
    constexpr int NCA = BM / 8, NCB = BN / 8, NCH = NCA + NCB;  // 16 or 12
    constexpr int CPW = NCH / 4;                                // 4 or 3
    constexpr int FN = BN / 32;                                 // 2 or 1
    __shared__ u16 As[2][BM][64];
    __shared__ u16 Bs[2][BN][64];

    const int tid  = threadIdx.x;
    const int wave = tid >> 6, lane = tid & 63;
    const int wm = (wave >> 1) * 32, wn = (wave & 1) * (BN / 2);
    const int lr = lane & 15, kh = lane >> 4;
    const int bm = blockIdx.y * BM, bn = blockIdx.x * BN;
    const int k0 = blockIdx.z * kPerZ;
    const int nt = kPerZ >> 6;

    const u16* Ab = A + (size_t)bm * Kd + k0;
    const u16* Bb = B + (size_t)bn * Kd + k0;

    const int l3  = lane >> 3;
    const int swz = ((lane & 7) ^ l3) * 8;

    f32x4 acc[2][FN];
#pragma unroll
    for (int a = 0; a < 2; ++a)
#pragma unroll
        for (int b = 0; b < FN; ++b) acc[a][b] = (f32x4){0.f, 0.f, 0.f, 0.f};

#define DMA_ISSUE(buf, kt)                                                         \
    {                                                                              \
        _Pragma("unroll")                                                          \
        for (int c = 0; c < CPW; ++c) {                                            \
            int cc = wave * CPW + c;                                               \
            if (cc < NCA) {                                                        \
                int row = cc * 8 + l3;                                             \
                gload16(Ab + (size_t)row * Kd + (kt) + swz, &As[buf][cc * 8][0]);  \
            } else {                                                               \
                int row = (cc - NCA) * 8 + l3;                                     \
                gload16(Bb + (size_t)row * Kd + (kt) + swz, &Bs[buf][(cc - NCA) * 8][0]); \
            }                                                                      \
        }                                                                          \
    }

    DMA_ISSUE(0, 0);
    int cur = 0;
    for (int t = 0; t < nt; ++t) {
        __syncthreads();
        if (t + 1 < nt) DMA_ISSUE(cur ^ 1, (t + 1) * 64);
#pragma unroll
        for (int ks = 0; ks < 2; ++ks) {
            short8 af[2], bfr[FN];
#pragma unroll
            for (int a = 0; a < 2; ++a) {
                int row = wm + a * 16 + lr;
                af[a] = *reinterpret_cast<const short8*>(
                    &As[cur][row][((ks * 4 + kh) ^ (lr & 7)) * 8]);
            }
#pragma unroll
            for (int b = 0; b < FN; ++b) {
                int row = wn + b * 16 + lr;
                bfr[b] = *reinterpret_cast<const short8*>(
                    &Bs[cur][row][((ks * 4 + kh) ^ (lr & 7)) * 8]);
            }
#pragma unroll
            for (int a = 0; a < 2; ++a)
#pragma unroll
                for (int b = 0; b < FN; ++b)
                    acc[a][b] = __builtin_amdgcn_mfma_f32_16x16x32_bf16(af[a], bfr[b], acc[a][b], 0, 0, 0);
        }
        cur ^= 1;
    }

    const int r0 = kh * 4;   // D: row=(lane>>4)*4+reg, col=lane&15
#pragma unroll
    for (int a = 0; a < 2; ++a) {
#pragma unroll
        for (int b = 0; b < FN; ++b) {
#pragma unroll
            for (int r = 0; r < 4; ++r) {
                int row = bm + wm + a * 16 + r0 + r;
                int col = bn + wn + b * 16 + lr;
                float v = acc[a][b][r];
                if (EPI == 0) {
                    ((float*)Cout)[((size_t)blockIdx.z * M + row) * N + col] = v;
                } else if (EPI == 1) {
                    v += bf2f(((const u16*)aux)[(size_t)row * N + col]);
                    ((u16*)Cout)[(size_t)row * N + col] = f2bf(v);
                } else if (EPI == 2) {
                    v = geluf(v + ((const float*)aux)[col]);
                    if (OUTF32) ((float*)Cout)[(size_t)row * N + col] = v;
                    else        ((u16*)Cout)[(size_t)row * N + col] = f2bf(v);
                } else {  // EPI == 3: gelu -> spline features -> FEAT
                    v = geluf(v + ((const float*)aux)[col]);
                    float f[NFEAT];
                    features9(v, f);
                    u16* o = (u16*)Cout + (size_t)row * (NFEAT * TDIM) + col;
#pragma unroll
                    for (int j = 0; j < NFEAT; ++j) o[j * TDIM] = f2bf(f[j]);
                }
            }
        }
    }
}

// ---------------------------------------------------------------------------
// launch
// ---------------------------------------------------------------------------
extern "C" void kernel_launch(void* const* d_in, const int* in_sizes, int n_in,
                              void* d_out, int out_size, void* d_ws, size_t ws_size,
                              hipStream_t stream) {
    const float* x            = (const float*)d_in[0];
    const float* tm1_ln_w     = (const float*)d_in[1];
    const float* tm1_ln_b     = (const float*)d_in[2];
    const float* tm1_k1_base  = (const float*)d_in[3];
    const float* tm1_k1_spl   = (const float*)d_in[4];
    const float* tm1_k2_base  = (const float*)d_in[5];
    const float* tm1_k2_spl   = (const float*)d_in[6];
    const float* g1_w         = (const float*)d_in[8];
    const float* g1_b         = (const float*)d_in[9];
    const float* k1_base      = (const float*)d_in[10];
    const float* k1_spl       = (const float*)d_in[11];
    const float* tm_ln_w      = (const float*)d_in[12];
    const float* tm_ln_b      = (const float*)d_in[13];
    const float* tm_k1_base   = (const float*)d_in[14];
    const float* tm_k1_spl    = (const float*)d_in[15];
    const float* tm_k2_base   = (const float*)d_in[16];
    const float* tm_k2_spl    = (const float*)d_in[17];
    const float* g2_w         = (const float*)d_in[19];
    const float* g2_b         = (const float*)d_in[20];
    const float* k2_base      = (const float*)d_in[21];
    const float* k2_spl       = (const float*)d_in[22];

    float* out = (float*)d_out;

    // ---- workspace layout -------------------------------------------------
    char* w = (char*)d_ws;
    u16*   FEATA = (u16*)w;   w += (size_t)M_ROWS * 4608 * 2;
    u16*   FEATB = (u16*)w;   w += (size_t)M_ROWS * 4608 * 2;
    u16*   FEAT2 = (u16*)w;   w += (size_t)M_ROWS * 576 * 2;
    float* PART  = (float*)w; w += (size_t)BZ * M_ROWS * 512 * 4;  // also HZ x 2048 x 64
    u16*   XB    = (u16*)w;   w += (size_t)M_ROWS * 512 * 2;
    u16*   BUF1  = (u16*)w;   w += (size_t)M_ROWS * 512 * 2;
    u16*   BUF2  = (u16*)w;   w += (size_t)M_ROWS * 512 * 2;
    u16*   W1a   = (u16*)w;   w += (size_t)64 * 4608 * 2;
    u16*   W1b   = (u16*)w;   w += (size_t)64 * 4608 * 2;
    u16*   W2a   = (u16*)w;   w += (size_t)512 * 576 * 2;
    u16*   W2b   = (u16*)w;   w += (size_t)512 * 576 * 2;
    u16*   WE1   = (u16*)w;   w += (size_t)512 * 512 * 2;
    u16*   WE2   = (u16*)w;   w += (size_t)512 * 512 * 2;
    u16*   KX1   = (u16*)w;   w += (size_t)512 * 4608 * 2;
    u16*   KX2   = (u16*)w;   w += (size_t)512 * 4608 * 2;
    float* LNT   = (float*)w; w += (size_t)4 * 65536 * 4;
    float* SR    = (float*)w; w += 64 * 4;
    const float* LNT0w = LNT, *LNT0b = LNT + 65536;
    const float* LNT2w = LNT + 131072, *LNT2b = LNT + 196608;

    // ---- merged prep (weights, LN transpose, stats zeroing) ---------------
    PrepPtrs p;
    p.g1_w = g1_w; p.g2_w = g2_w;
    p.b1 = tm1_k1_base; p.s1 = tm1_k1_spl;
    p.b2 = tm_k1_base;  p.s2 = tm_k1_spl;
    p.b3 = tm1_k2_base; p.s3 = tm1_k2_spl;
    p.b4 = tm_k2_base;  p.s4 = tm_k2_spl;
    p.b5 = k1_base;     p.s5 = k1_spl;
    p.b6 = k2_base;     p.s6 = k2_spl;
    p.WE1 = WE1; p.WE2 = WE2; p.W1a = W1a; p.W1b = W1b;
    p.W2a = W2a; p.W2b = W2b; p.KX1 = KX1; p.KX2 = KX2;
    p.ln1w = tm1_ln_w; p.ln1b = tm1_ln_b; p.ln2w = tm_ln_w; p.ln2b = tm_ln_b;
    p.LNT = LNT; p.SR = SR;
    prep_all<<<5633, 256, 0, stream>>>(p);

    // ---- branch 1 + branch 2 feature prep ---------------------------------
    stats1_convert<<<1024, 256, 0, stream>>>(x, XB, SR);
    build_feat_dual<<<M_ROWS, 128, 0, stream>>>(x, SR, LNT0w, LNT0b, FEATA, FEATB);

    // ---- branch 1: tm1 = token_mixing(x); y1 = gelu(tm1 @ WE1 + b1) -> out
    gemm_dma<64, 64, 0, true><<<dim3(1, 32, HZ), 256, 0, stream>>>(FEATA, W1a, PART, nullptr, M_ROWS, 64, 4608, 4608 / HZ);
    build_feat2<<<512, 256, 0, stream>>>(PART, FEAT2);
    gemm_dma<64, 32, 1, false><<<dim3(16, 32, 1), 256, 0, stream>>>(FEAT2, W2a, BUF1, XB, M_ROWS, 512, 576, 576);
    gemm_dma<64, 32, 2, true><<<dim3(16, 32, 1), 256, 0, stream>>>(BUF1, WE1, out, g1_b, M_ROWS, 512, 512, 512);

    // ---- branch 2: cm = kan(x); tm = token_mixing(cm); y2; z = kan(y2) ----
    gemm_big<<<512, 512, 0, stream>>>(FEATB, KX1, PART);
    reduce4_bf16_stats<<<1024, 256, 0, stream>>>(PART, BUF2, SR + 32);

    build_feat_ln<<<M_ROWS, 128, 0, stream>>>(BUF2, SR + 32, LNT2w, LNT2b, FEATA);
    gemm_dma<64, 64, 0, true><<<dim3(1, 32, HZ), 256, 0, stream>>>(FEATA, W1b, PART, nullptr, M_ROWS, 64, 4608, 4608 / HZ);
    build_feat2<<<512, 256, 0, stream>>>(PART, FEAT2);
    gemm_dma<64, 32, 1, false><<<dim3(16, 32, 1), 256, 0, stream>>>(FEAT2, W2b, BUF1, BUF2, M_ROWS, 512, 576, 576);
    // y2 GEMM: gelu + spline features fused -> FEATB (reused)
    gemm_dma<64, 32, 3, false><<<dim3(16, 32, 1), 256, 0, stream>>>(BUF1, WE2, FEATB, g2_b, M_ROWS, 512, 512, 512);

    gemm_big<<<512, 512, 0, stream>>>(FEATB, KX2, PART);
    reduce4_add<<<1024, 256, 0, stream>>>(PART, out);
}